// Round 10
// baseline (1340.359 us; speedup 1.0000x reference)
//
#include <hip/hip_runtime.h>
#include <hip/hip_bf16.h>
#include <stdint.h>

typedef short bf16x8 __attribute__((ext_vector_type(8)));   // 8 bf16 in 4 VGPRs
typedef float f32x4 __attribute__((ext_vector_type(4)));
typedef unsigned short u16;
typedef u16 u16x8 __attribute__((ext_vector_type(8)));

__device__ __forceinline__ u16 f2bf(float x) {
  __hip_bfloat16 h = __float2bfloat16(x);
  return *reinterpret_cast<u16*>(&h);
}
__device__ __forceinline__ float bf2f(u16 v) {
  unsigned u = (unsigned)v << 16;
  return *reinterpret_cast<float*>(&u);
}

// async global->LDS, 16B per lane. LDS dest is wave-uniform base + lane*16 (m104/m108).
__device__ __forceinline__ void gload_lds16(const void* g, const void* lds_base) {
  __builtin_amdgcn_global_load_lds(
      (const __attribute__((address_space(1))) unsigned int*)(uintptr_t)g,
      (__attribute__((address_space(3))) unsigned int*)(uintptr_t)lds_base,
      16, 0, 0);
}

#define BAR() __builtin_amdgcn_s_barrier()

// ---------------- LayerNorm + cast to bf16 (rows of q,k,v), float4-vectorized ----------------
__global__ __launch_bounds__(256) void ln_cast_kernel(
    const float* __restrict__ q, const float* __restrict__ k, const float* __restrict__ v,
    const float* __restrict__ lw, const float* __restrict__ lb, u16* __restrict__ out) {
  int row = blockIdx.x;
  const float* x;
  if (row < 8192) x = q + (size_t)row * 768;
  else if (row < 16384) x = k + (size_t)(row - 8192) * 768;
  else x = v + (size_t)(row - 16384) * 768;
  int t = threadIdx.x;
  __shared__ float red[4];
  __shared__ float red2[4];
  float4 a = (t < 192) ? ((const float4*)x)[t] : make_float4(0.f, 0.f, 0.f, 0.f);
  float s = a.x + a.y + a.z + a.w;
  for (int o = 32; o; o >>= 1) s += __shfl_down(s, o, 64);
  if ((t & 63) == 0) red[t >> 6] = s;
  __syncthreads();
  float mean = (red[0] + red[1] + red[2]) * (1.0f / 768.0f);
  float4 d = make_float4(a.x - mean, a.y - mean, a.z - mean, a.w - mean);
  float vs = (t < 192) ? (d.x * d.x + d.y * d.y + d.z * d.z + d.w * d.w) : 0.f;
  for (int o = 32; o; o >>= 1) vs += __shfl_down(vs, o, 64);
  if ((t & 63) == 0) red2[t >> 6] = vs;
  __syncthreads();
  float var = (red2[0] + red2[1] + red2[2]) * (1.0f / 768.0f);
  float rstd = rsqrtf(var + 1e-5f);
  if (t < 192) {
    float4 wv = ((const float4*)lw)[t];
    float4 bv = ((const float4*)lb)[t];
    ushort4 o;
    o.x = f2bf(d.x * rstd * wv.x + bv.x);
    o.y = f2bf(d.y * rstd * wv.y + bv.y);
    o.z = f2bf(d.z * rstd * wv.z + bv.z);
    o.w = f2bf(d.w * rstd * wv.w + bv.w);
    ((ushort4*)(out + (size_t)row * 768))[t] = o;
  }
}

// ---------------- fp32 -> bf16 cast (weights) ----------------
__global__ __launch_bounds__(256) void cast_f32_bf16(const float* __restrict__ in,
                                                     u16* __restrict__ out, int n4) {
  int i = blockIdx.x * 256 + threadIdx.x;
  if (i < n4) {
    float4 vv = ((const float4*)in)[i];
    ushort4 o;
    o.x = f2bf(vv.x); o.y = f2bf(vv.y); o.z = f2bf(vv.z); o.w = f2bf(vv.w);
    ((ushort4*)out)[i] = o;
  }
}

// ---------------- zero fp32 buffer ----------------
__global__ __launch_bounds__(256) void zero_f32(float* __restrict__ p, int n) {
  int i = blockIdx.x * 256 + threadIdx.x;
  if (i < n) p[i] = 0.0f;
}

// ---------------- 64x64 tiled bf16 transpose: vn[8192][768] -> vnT[768][8192] ----------------
__global__ __launch_bounds__(256) void transpose64(const u16* __restrict__ in, u16* __restrict__ out) {
  __shared__ __align__(16) u16 tile[64][72];
  int b = blockIdx.x;
  int tr = b / 12, tc = b % 12;
  int t = threadIdx.x;
  int r = t >> 3;
  int cb = (t & 7) << 3;
#pragma unroll
  for (int i = 0; i < 2; i++) {
    int row = r + i * 32;
    const u16* src = in + (size_t)(tr * 64 + row) * 768 + tc * 64 + cb;
    *(uint4*)&tile[row][cb] = *(const uint4*)src;
  }
  __syncthreads();
#pragma unroll
  for (int i = 0; i < 2; i++) {
    int oc = r + i * 32;
    u16x8 tmp;
#pragma unroll
    for (int j = 0; j < 8; j++) tmp[j] = tile[cb + j][oc];
    u16* dst = out + (size_t)(tc * 64 + oc) * 8192 + tr * 64 + cb;
    *(u16x8*)dst = tmp;
  }
}

// ---------------- sum 4 bf16 partials, scale by 1/rowsum, write bf16 ----------------
__global__ __launch_bounds__(256) void reduce4_scale(
    const u16* __restrict__ p0, const u16* __restrict__ p1,
    const u16* __restrict__ p2, const u16* __restrict__ p3,
    const float* __restrict__ rowsum, u16* __restrict__ out, int n8) {
  int i = blockIdx.x * 256 + threadIdx.x;
  if (i < n8) {
    float inv = 1.0f / rowsum[i / 96];
    u16x8 a = ((const u16x8*)p0)[i];
    u16x8 b = ((const u16x8*)p1)[i];
    u16x8 c = ((const u16x8*)p2)[i];
    u16x8 d = ((const u16x8*)p3)[i];
    u16x8 o;
#pragma unroll
    for (int j = 0; j < 8; j++)
      o[j] = f2bf((bf2f(a[j]) + bf2f(b[j]) + bf2f(c[j]) + bf2f(d[j])) * inv);
    ((u16x8*)out)[i] = o;
  }
}

// ========== QK^T + exp, 256x256 tile, BK=32, 2-buffer / 64KB LDS -> 2 blocks/CU ==========
// C[8192][8192] bf16 = exp(A @ B^T * scale); rowsum atomics.
// 512 thr = 8 waves (2M x 4N), per-wave 128x64 out. 24 K-tiles of 32.
// Phase T: ds_read buf[T&1] | stage T+1 -> buf[T&1^1] | BAR | 32 MFMA | vmcnt(0) | BAR.
// RAW: per-phase drain. WAR: stage targets the buffer whose reads completed last phase.
// The drain stall is hidden by the SECOND co-resident block (m114 mechanism) — the thing
// all previous 128KB/1-block variants lacked. LDS 64 KB, VGPR capped 128 -> 2 blocks/CU.
// Swizzle (64B rows): byte ^= (((row>>1)&3)<<4), involution on both sides (rule 21).
__global__ __launch_bounds__(512, 4) void qk_exp_256(
    const u16* __restrict__ A, const u16* __restrict__ B, u16* __restrict__ C,
    float* __restrict__ rowsum, float scale) {
  __shared__ __align__(16) u16 lds[2 * 2 * 8192];  // 64 KB: buf b: A @ b*32KB, B @ b*32KB+16KB
  int orig = blockIdx.x;               // 1024 blocks, %8==0
  int xcd = orig & 7, i = orig >> 3;
  int tm = xcd * 4 + (i & 3), tn = i >> 2;
  const int t = threadIdx.x, l = t & 63, w = t >> 6;
  const int wr = w >> 2, wc = w & 3;   // 2 x 4 wave grid
  const int lr = l & 15, lq = l >> 4;
  const int colb = lq * 16;

  f32x4 acc[8][4];
#pragma unroll
  for (int m = 0; m < 8; m++)
#pragma unroll
    for (int n = 0; n < 4; n++) acc[m][n] = (f32x4){0.f, 0.f, 0.f, 0.f};

  const size_t rA0 = (size_t)tm * 256, rB0 = (size_t)tn * 256;

  // ---- hoisted addressing ----
  const char* gsrc[4];   // per-lane global source addr at tile 0 (idx: 0,1=A halves; 2,3=B)
  int ldsoff[4];
#pragma unroll
  for (int idx = 0; idx < 4; idx++) {
    const u16* src = (idx < 2) ? A : B;
    size_t r0 = (idx < 2) ? rA0 : rB0;
    int p = idx & 1;
    int x = p * 8192 + t * 16;                  // byte offset in the matrix's 16KB tile
    int r = x >> 6;                             // row 0..255
    int cb = (x & 63) ^ (((r >> 1) & 3) << 4);  // pre-swizzled source byte col
    gsrc[idx] = (const char*)(src + (r0 + r) * 768) + cb;
    ldsoff[idx] = ((idx < 2) ? 0 : 16384) + p * 8192 + w * 1024;
  }
  int offA[2][4], offB[4];                      // swizzled LDS read byte offsets (buf 0)
#pragma unroll
  for (int mh = 0; mh < 2; mh++)
#pragma unroll
    for (int mf = 0; mf < 4; mf++) {
      int row = wr * 128 + (mh * 4 + mf) * 16 + lr;
      int x = row * 64 + colb;
      offA[mh][mf] = x ^ (((row >> 1) & 3) << 4);
    }
#pragma unroll
  for (int nf = 0; nf < 4; nf++) {
    int row = wc * 64 + nf * 16 + lr;
    int x = row * 64 + colb;
    offB[nf] = 16384 + (x ^ (((row >> 1) & 3) << 4));
  }

#define SCALL(BUF, TT, IDX)                                                  \
  gload_lds16(gsrc[IDX] + (size_t)(TT) * 64,                                 \
              (const char*)lds + (BUF) * 32768 + ldsoff[IDX])

  auto LOADA = [&](bf16x8 (&aF)[4], int b, int mh) {
#pragma unroll
    for (int mf = 0; mf < 4; mf++)
      aF[mf] = *(const bf16x8*)((const char*)lds + b * 32768 + offA[mh][mf]);
  };
  auto LOADB = [&](bf16x8 (&bF)[4], int b) {
#pragma unroll
    for (int nf = 0; nf < 4; nf++)
      bF[nf] = *(const bf16x8*)((const char*)lds + b * 32768 + offB[nf]);
  };
  auto MM32 = [&](bf16x8 (&aF)[4], bf16x8 (&aG)[4], bf16x8 (&bF)[4]) {
    __builtin_amdgcn_s_setprio(1);
#pragma unroll
    for (int mf = 0; mf < 4; mf++)
#pragma unroll
      for (int nf = 0; nf < 4; nf++)
        acc[mf][nf] = __builtin_amdgcn_mfma_f32_16x16x32_bf16(
            aF[mf], bF[nf], acc[mf][nf], 0, 0, 0);
#pragma unroll
    for (int mf = 0; mf < 4; mf++)
#pragma unroll
      for (int nf = 0; nf < 4; nf++)
        acc[4 + mf][nf] = __builtin_amdgcn_mfma_f32_16x16x32_bf16(
            aG[mf], bF[nf], acc[4 + mf][nf], 0, 0, 0);
    __builtin_amdgcn_s_setprio(0);
  };

  // ---- prologue: stage tile 0 into buf 0, drain, barrier ----
  SCALL(0, 0, 0); SCALL(0, 0, 1); SCALL(0, 0, 2); SCALL(0, 0, 3);
  asm volatile("s_waitcnt vmcnt(0)" ::: "memory");
  BAR();

  // ---- main loop: 24 phases, stage T+1 into opposite buffer ----
  for (int T = 0; T < 24; T++) {
    const int cur = T & 1, nxt = cur ^ 1;
    bf16x8 aF[4], aG[4], bF[4];
    LOADA(aF, cur, 0);
    LOADA(aG, cur, 1);
    LOADB(bF, cur);
    if (T < 23) {
      SCALL(nxt, T + 1, 0); SCALL(nxt, T + 1, 1);
      SCALL(nxt, T + 1, 2); SCALL(nxt, T + 1, 3);
    }
    BAR();
    MM32(aF, aG, bF);
    asm volatile("s_waitcnt vmcnt(0)" ::: "memory");
    BAR();
  }

#undef SCALL

  // ---- epilogue: exp + store + per-row sums (C/D layout: col=lane&15, row=(lane>>4)*4+j) ----
  float rs[8][4];
#pragma unroll
  for (int m = 0; m < 8; m++)
#pragma unroll
    for (int j = 0; j < 4; j++) rs[m][j] = 0.0f;
  const size_t rowBase = rA0 + (size_t)wr * 128;
  const int colBase = tn * 256 + wc * 64;
#pragma unroll
  for (int mi = 0; mi < 8; mi++) {
    size_t row0 = rowBase + mi * 16 + lq * 4;
#pragma unroll
    for (int nf = 0; nf < 4; nf++) {
      int col = colBase + nf * 16 + lr;
#pragma unroll
      for (int j = 0; j < 4; j++) {
        float e = __expf(acc[mi][nf][j] * scale);
        C[(row0 + j) * 8192 + col] = f2bf(e);
        rs[mi][j] += e;
      }
    }
  }
#pragma unroll
  for (int mi = 0; mi < 8; mi++)
#pragma unroll
    for (int j = 0; j < 4; j++) {
      float r = rs[mi][j];
      r += __shfl_xor(r, 1); r += __shfl_xor(r, 2);
      r += __shfl_xor(r, 4); r += __shfl_xor(r, 8);
      if (lr == 0) atomicAdd(&rowsum[rowBase + mi * 16 + lq * 4 + j], r);
    }
}

// ---------------- bt-GEMM (m97 128^2 structure) for qkv / PV / proj ----------------
// MODE 0: bf16 out * scale; MODE 2: f32 out + bias[col]
template <int MODE>
__global__ __launch_bounds__(256, 2) void gemm_bt(
    const u16* __restrict__ A0, const u16* __restrict__ B0,
    void* __restrict__ Cv0, void* __restrict__ Cv1,
    int M, int N, int K, int lda, int ldb, int ldc,
    float scale, const float* __restrict__ bias, size_t cSplitStride) {
  __shared__ __align__(16) u16 sA[128 * 64];
  __shared__ __align__(16) u16 sB[128 * 64];
  const int z = blockIdx.y;
  const u16* A = A0 + (size_t)z * (size_t)K;
  const u16* B = B0 + (size_t)z * (size_t)K;
  u16* Cb = (z < 2) ? ((u16*)Cv0 + (size_t)z * cSplitStride)
                    : ((u16*)Cv1 + (size_t)(z - 2) * cSplitStride);
  const int nTn = N >> 7;
  int nwg = gridDim.x, orig = blockIdx.x;
  int qq = nwg >> 3, rr = nwg & 7;
  int xcd = orig & 7, loc = orig >> 3;
  int wg = (xcd < rr ? xcd * (qq + 1) : rr * (qq + 1) + (xcd - rr) * qq) + loc;
  int tm = wg / nTn, tn = wg % nTn;

  const int t = threadIdx.x, l = t & 63, w = t >> 6;
  const int wr = w >> 1, wc = w & 1;
  const int lr = l & 15, kg = (l >> 4) << 3;

  f32x4 acc[4][4];
#pragma unroll
  for (int m = 0; m < 4; m++)
#pragma unroll
    for (int n = 0; n < 4; n++) acc[m][n] = (f32x4){0.f, 0.f, 0.f, 0.f};

  const size_t rowA0 = (size_t)tm * 128;
  const size_t rowB0 = (size_t)tn * 128;
  const int nk = K >> 6;
  for (int kt = 0; kt < nk; kt++) {
    const int k0 = kt << 6;
#pragma unroll
    for (int i = 0; i < 4; i++) {
      int chunk = i * 256 + t;
      int row = chunk >> 3;
      int col = (chunk & 7) << 3;
      gload_lds16(A + (rowA0 + row) * lda + k0 + col, (const char*)sA + (i * 256 + w * 64) * 16);
      gload_lds16(B + (rowB0 + row) * ldb + k0 + col, (const char*)sB + (i * 256 + w * 64) * 16);
    }
    __syncthreads();
#pragma unroll
    for (int kk = 0; kk < 2; kk++) {
      bf16x8 af[4], bfv[4];
#pragma unroll
      for (int m = 0; m < 4; m++)
        af[m] = *(const bf16x8*)&sA[(wr * 64 + m * 16 + lr) * 64 + kk * 32 + kg];
#pragma unroll
      for (int n = 0; n < 4; n++)
        bfv[n] = *(const bf16x8*)&sB[(wc * 64 + n * 16 + lr) * 64 + kk * 32 + kg];
#pragma unroll
      for (int m = 0; m < 4; m++)
#pragma unroll
        for (int n = 0; n < 4; n++)
          acc[m][n] = __builtin_amdgcn_mfma_f32_16x16x32_bf16(af[m], bfv[n], acc[m][n], 0, 0, 0);
    }
    __syncthreads();
  }
#pragma unroll
  for (int m = 0; m < 4; m++) {
    int row = tm * 128 + wr * 64 + m * 16 + ((l >> 4) << 2);
#pragma unroll
    for (int n = 0; n < 4; n++) {
      int col = tn * 128 + wc * 64 + n * 16 + lr;
#pragma unroll
      for (int j = 0; j < 4; j++) {
        float vl = acc[m][n][j];
        if (MODE == 0) Cb[(size_t)(row + j) * ldc + col] = f2bf(vl * scale);
        else ((float*)Cv0)[(size_t)(row + j) * ldc + col] = vl + bias[col];
      }
    }
  }
}

// ---------------- host ----------------
extern "C" void kernel_launch(void* const* d_in, const int* in_sizes, int n_in,
                              void* d_out, int out_size, void* d_ws, size_t ws_size,
                              hipStream_t stream) {
  const float* q  = (const float*)d_in[0];
  const float* k  = (const float*)d_in[1];
  const float* v  = (const float*)d_in[2];
  const float* lw = (const float*)d_in[3];
  const float* lb = (const float*)d_in[4];
  const float* Wq = (const float*)d_in[5];
  const float* Wp = (const float*)d_in[6];
  const float* bp = (const float*)d_in[7];

  char* ws = (char*)d_ws;
  size_t off = 0;
  auto alloc = [&](size_t b) { size_t o = off; off += (b + 255) & ~(size_t)255; return o; };
  size_t o_ln = alloc((size_t)24576 * 768 * 2);  // LN(q,k,v) bf16; later: vnT | p0 | p1
  size_t o_pj = alloc((size_t)24576 * 768 * 2);  // qn,kn,vn bf16; vn region later: rowsum
  size_t o_wq = alloc((size_t)768 * 768 * 2);
  size_t o_wp = alloc((size_t)768 * 768 * 2);
  u16* lnbuf = (u16*)(ws + o_ln);
  u16* pj    = (u16*)(ws + o_pj);
  u16* wqb   = (u16*)(ws + o_wq);
  u16* wpb   = (u16*)(ws + o_wp);
  const size_t NS = (size_t)8192 * 768;
  u16* vnT = lnbuf;
  u16* p0  = lnbuf + NS;
  u16* p1  = lnbuf + 2 * NS;
  float* rowsum = (float*)(pj + 2 * NS);  // vn rows dead after transpose
  u16* p2 = (u16*)d_out;                   // partials 2,3 in d_out (overwritten by proj)
  u16* p3 = p2 + NS;
  size_t fixedEnd = off;
  u16* Sbuf = (u16*)(ws + fixedEnd);       // P' = exp(S*scale) bf16, 8192x8192

  const float scale = 0.03608439182435161f;  // 1/sqrt(768)

  ln_cast_kernel<<<dim3(24576), dim3(256), 0, stream>>>(q, k, v, lw, lb, lnbuf);
  cast_f32_bf16<<<dim3(576), dim3(256), 0, stream>>>(Wq, wqb, 147456);
  cast_f32_bf16<<<dim3(576), dim3(256), 0, stream>>>(Wp, wpb, 147456);

  // qn/kn/vn = LN(x) @ W_qkv^T
  gemm_bt<0><<<dim3(1152), dim3(256), 0, stream>>>(lnbuf, wqb, (void*)pj, (void*)pj,
      24576, 768, 768, 768, 768, 768, 1.0f, (const float*)nullptr, 0);

  transpose64<<<dim3(1536), dim3(256), 0, stream>>>(pj + (size_t)16384 * 768, vnT);
  zero_f32<<<dim3(32), dim3(256), 0, stream>>>(rowsum, 8192);

  // P' = exp(qn @ kn^T * scale), rowsum via atomics — 64KB 2-buf, 2 blocks/CU
  qk_exp_256<<<dim3(1024), dim3(512), 0, stream>>>(pj, pj + NS, Sbuf, rowsum, scale);

  // attn partials = P' @ vn, 4-way split-K
  gemm_bt<0><<<dim3(384, 4), dim3(256), 0, stream>>>(
      Sbuf, vnT, (void*)p0, (void*)p2,
      8192, 768, 2048, 8192, 8192, 768, 1.0f, (const float*)nullptr, NS);

  // attn_out = (p0+p1+p2+p3) / rowsum
  reduce4_scale<<<dim3(3072), dim3(256), 0, stream>>>(p0, p1, p2, p3, rowsum, p0, (int)(NS / 8));

  // out = attn_out @ W_proj^T + b_proj
  gemm_bt<2><<<dim3(384), dim3(256), 0, stream>>>(p0, wpb, d_out, d_out,
      8192, 768, 768, 768, 768, 768, 1.0f, bp, 0);
}

// Round 11
// 356.239 us; speedup vs baseline: 3.7625x; 3.7625x over previous
//
#include <hip/hip_runtime.h>
#include <hip/hip_bf16.h>
#include <stdint.h>

typedef short bf16x8 __attribute__((ext_vector_type(8)));   // 8 bf16 in 4 VGPRs
typedef float f32x4 __attribute__((ext_vector_type(4)));
typedef unsigned short u16;
typedef u16 u16x8 __attribute__((ext_vector_type(8)));

__device__ __forceinline__ u16 f2bf(float x) {
  __hip_bfloat16 h = __float2bfloat16(x);
  return *reinterpret_cast<u16*>(&h);
}
__device__ __forceinline__ float bf2f(u16 v) {
  unsigned u = (unsigned)v << 16;
  return *reinterpret_cast<float*>(&u);
}

// async global->LDS, 16B per lane. LDS dest is wave-uniform base + lane*16 (m104/m108).
__device__ __forceinline__ void gload_lds16(const void* g, const void* lds_base) {
  __builtin_amdgcn_global_load_lds(
      (const __attribute__((address_space(1))) unsigned int*)(uintptr_t)g,
      (__attribute__((address_space(3))) unsigned int*)(uintptr_t)lds_base,
      16, 0, 0);
}

#define BAR() __builtin_amdgcn_s_barrier()

// ---------------- LayerNorm + cast to bf16 (rows of q,k,v), float4-vectorized ----------------
__global__ __launch_bounds__(256) void ln_cast_kernel(
    const float* __restrict__ q, const float* __restrict__ k, const float* __restrict__ v,
    const float* __restrict__ lw, const float* __restrict__ lb, u16* __restrict__ out) {
  int row = blockIdx.x;
  const float* x;
  if (row < 8192) x = q + (size_t)row * 768;
  else if (row < 16384) x = k + (size_t)(row - 8192) * 768;
  else x = v + (size_t)(row - 16384) * 768;
  int t = threadIdx.x;
  __shared__ float red[4];
  __shared__ float red2[4];
  float4 a = (t < 192) ? ((const float4*)x)[t] : make_float4(0.f, 0.f, 0.f, 0.f);
  float s = a.x + a.y + a.z + a.w;
  for (int o = 32; o; o >>= 1) s += __shfl_down(s, o, 64);
  if ((t & 63) == 0) red[t >> 6] = s;
  __syncthreads();
  float mean = (red[0] + red[1] + red[2]) * (1.0f / 768.0f);
  float4 d = make_float4(a.x - mean, a.y - mean, a.z - mean, a.w - mean);
  float vs = (t < 192) ? (d.x * d.x + d.y * d.y + d.z * d.z + d.w * d.w) : 0.f;
  for (int o = 32; o; o >>= 1) vs += __shfl_down(vs, o, 64);
  if ((t & 63) == 0) red2[t >> 6] = vs;
  __syncthreads();
  float var = (red2[0] + red2[1] + red2[2]) * (1.0f / 768.0f);
  float rstd = rsqrtf(var + 1e-5f);
  if (t < 192) {
    float4 wv = ((const float4*)lw)[t];
    float4 bv = ((const float4*)lb)[t];
    ushort4 o;
    o.x = f2bf(d.x * rstd * wv.x + bv.x);
    o.y = f2bf(d.y * rstd * wv.y + bv.y);
    o.z = f2bf(d.z * rstd * wv.z + bv.z);
    o.w = f2bf(d.w * rstd * wv.w + bv.w);
    ((ushort4*)(out + (size_t)row * 768))[t] = o;
  }
}

// ---------------- fp32 -> bf16 cast (weights) ----------------
__global__ __launch_bounds__(256) void cast_f32_bf16(const float* __restrict__ in,
                                                     u16* __restrict__ out, int n4) {
  int i = blockIdx.x * 256 + threadIdx.x;
  if (i < n4) {
    float4 vv = ((const float4*)in)[i];
    ushort4 o;
    o.x = f2bf(vv.x); o.y = f2bf(vv.y); o.z = f2bf(vv.z); o.w = f2bf(vv.w);
    ((ushort4*)out)[i] = o;
  }
}

// ---------------- zero fp32 buffer ----------------
__global__ __launch_bounds__(256) void zero_f32(float* __restrict__ p, int n) {
  int i = blockIdx.x * 256 + threadIdx.x;
  if (i < n) p[i] = 0.0f;
}

// ---------------- sum 4 bf16 partials, scale by 1/rowsum, write bf16 ----------------
__global__ __launch_bounds__(256) void reduce4_scale(
    const u16* __restrict__ p0, const u16* __restrict__ p1,
    const u16* __restrict__ p2, const u16* __restrict__ p3,
    const float* __restrict__ rowsum, u16* __restrict__ out, int n8) {
  int i = blockIdx.x * 256 + threadIdx.x;
  if (i < n8) {
    float inv = 1.0f / rowsum[i / 96];
    u16x8 a = ((const u16x8*)p0)[i];
    u16x8 b = ((const u16x8*)p1)[i];
    u16x8 c = ((const u16x8*)p2)[i];
    u16x8 d = ((const u16x8*)p3)[i];
    u16x8 o;
#pragma unroll
    for (int j = 0; j < 8; j++)
      o[j] = f2bf((bf2f(a[j]) + bf2f(b[j]) + bf2f(c[j]) + bf2f(d[j])) * inv);
    ((u16x8*)out)[i] = o;
  }
}

// ========== QK^T + exp, 256x256 tile, BK=32, 4-deep rotation, stage-ahead-3 ==========
// ROUND-9 VERSION (proven 155.7us) — do NOT raise launch_bounds min-waves: forcing 4
// waves/EU halves the unified VGPR+AGPR budget to 128/wave -> acc[8][4] spills (round-10:
// VGPR=64, 2.2GB scratch traffic, 8.5x slowdown).
__global__ __launch_bounds__(512, 2) void qk_exp_256(
    const u16* __restrict__ A, const u16* __restrict__ B, u16* __restrict__ C,
    float* __restrict__ rowsum, float scale) {
  __shared__ __align__(16) u16 lds[8 * 256 * 32];  // 128 KB: A bufs 0-3 | B bufs 0-3
  int orig = blockIdx.x;               // 1024 blocks, %8==0
  int xcd = orig & 7, i = orig >> 3;
  int tm = xcd * 4 + (i & 3), tn = i >> 2;
  const int t = threadIdx.x, l = t & 63, w = t >> 6;
  const int wr = w >> 2, wc = w & 3;   // 2 x 4 wave grid
  const int lr = l & 15, lq = l >> 4;
  const int colb = lq * 16;

  f32x4 acc[8][4];
#pragma unroll
  for (int m = 0; m < 8; m++)
#pragma unroll
    for (int n = 0; n < 4; n++) acc[m][n] = (f32x4){0.f, 0.f, 0.f, 0.f};

  const size_t rA0 = (size_t)tm * 256, rB0 = (size_t)tn * 256;

  // ---- hoisted addressing ----
  const char* gsrc[4];
  int ldsoff[4];
#pragma unroll
  for (int idx = 0; idx < 4; idx++) {
    const u16* src = (idx < 2) ? A : B;
    size_t r0 = (idx < 2) ? rA0 : rB0;
    int p = idx & 1;
    int x = p * 8192 + t * 16;
    int r = x >> 6;
    int cb = (x & 63) ^ (((r >> 1) & 3) << 4);
    gsrc[idx] = (const char*)(src + (r0 + r) * 768) + cb;
    ldsoff[idx] = ((idx < 2) ? 0 : 65536) + p * 8192 + w * 1024;
  }
  int offA[2][4], offB[4];
#pragma unroll
  for (int mh = 0; mh < 2; mh++)
#pragma unroll
    for (int mf = 0; mf < 4; mf++) {
      int row = wr * 128 + (mh * 4 + mf) * 16 + lr;
      int x = row * 64 + colb;
      offA[mh][mf] = x ^ (((row >> 1) & 3) << 4);
    }
#pragma unroll
  for (int nf = 0; nf < 4; nf++) {
    int row = wc * 64 + nf * 16 + lr;
    int x = row * 64 + colb;
    offB[nf] = 65536 + (x ^ (((row >> 1) & 3) << 4));
  }

#define SCALL(BUF, TT, IDX)                                                  \
  gload_lds16(gsrc[IDX] + (size_t)(TT) * 64,                                 \
              (const char*)lds + (BUF) * 16384 + ldsoff[IDX])

  auto LOADA = [&](bf16x8 (&aF)[4], int b, int mh) {
#pragma unroll
    for (int mf = 0; mf < 4; mf++)
      aF[mf] = *(const bf16x8*)((const char*)lds + b * 16384 + offA[mh][mf]);
  };
  auto LOADB = [&](bf16x8 (&bF)[4], int b) {
#pragma unroll
    for (int nf = 0; nf < 4; nf++)
      bF[nf] = *(const bf16x8*)((const char*)lds + b * 16384 + offB[nf]);
  };
  auto MM32 = [&](bf16x8 (&aF)[4], bf16x8 (&aG)[4], bf16x8 (&bF)[4]) {
    __builtin_amdgcn_s_setprio(1);
#pragma unroll
    for (int mf = 0; mf < 4; mf++)
#pragma unroll
      for (int nf = 0; nf < 4; nf++)
        acc[mf][nf] = __builtin_amdgcn_mfma_f32_16x16x32_bf16(
            aF[mf], bF[nf], acc[mf][nf], 0, 0, 0);
#pragma unroll
    for (int mf = 0; mf < 4; mf++)
#pragma unroll
      for (int nf = 0; nf < 4; nf++)
        acc[4 + mf][nf] = __builtin_amdgcn_mfma_f32_16x16x32_bf16(
            aG[mf], bF[nf], acc[4 + mf][nf], 0, 0, 0);
    __builtin_amdgcn_s_setprio(0);
  };

#define PHASE(CUR, SBUF, STAGET, DOSTAGE, VMN)                               \
  do {                                                                       \
    bf16x8 aF[4], aG[4], bF[4];                                              \
    LOADA(aF, CUR, 0);                                                       \
    LOADA(aG, CUR, 1);                                                       \
    LOADB(bF, CUR);                                                          \
    if (DOSTAGE) {                                                           \
      SCALL(SBUF, STAGET, 0); SCALL(SBUF, STAGET, 1);                        \
      SCALL(SBUF, STAGET, 2); SCALL(SBUF, STAGET, 3);                        \
    }                                                                        \
    BAR();                                                                   \
    MM32(aF, aG, bF);                                                        \
    if ((VMN) == 8) asm volatile("s_waitcnt vmcnt(8)" ::: "memory");         \
    else if ((VMN) == 4) asm volatile("s_waitcnt vmcnt(4)" ::: "memory");    \
    else if ((VMN) == 0) asm volatile("s_waitcnt vmcnt(0)" ::: "memory");    \
    BAR();                                                                   \
  } while (0)

  // ---- prologue: stage tiles 0,1,2; wait for tile 0 (8 loads stay in flight) ----
  SCALL(0, 0, 0); SCALL(0, 0, 1); SCALL(0, 0, 2); SCALL(0, 0, 3);
  SCALL(1, 1, 0); SCALL(1, 1, 1); SCALL(1, 1, 2); SCALL(1, 1, 3);
  SCALL(2, 2, 0); SCALL(2, 2, 1); SCALL(2, 2, 2); SCALL(2, 2, 3);
  asm volatile("s_waitcnt vmcnt(8)" ::: "memory");
  BAR();

  // ---- main loop: T in [0,20), stage T+3, steady vmcnt(8) ----
  for (int Tb = 0; Tb < 20; Tb += 4) {
    PHASE(0, 3, Tb + 3, 1, 8);
    PHASE(1, 0, Tb + 4, 1, 8);
    PHASE(2, 1, Tb + 5, 1, 8);
    PHASE(3, 2, Tb + 6, 1, 8);
  }
  // ---- peeled tail: T=20 (stage 23), 21, 22, 23 ----
  PHASE(0, 3, 23, 1, 8);
  PHASE(1, 0, 0, 0, 4);
  PHASE(2, 0, 0, 0, 0);
  PHASE(3, 0, 0, 0, -1);

#undef PHASE
#undef SCALL

  // ---- epilogue: exp + store + per-row sums (C/D layout: col=lane&15, row=(lane>>4)*4+j) ----
  float rs[8][4];
#pragma unroll
  for (int m = 0; m < 8; m++)
#pragma unroll
    for (int j = 0; j < 4; j++) rs[m][j] = 0.0f;
  const size_t rowBase = rA0 + (size_t)wr * 128;
  const int colBase = tn * 256 + wc * 64;
#pragma unroll
  for (int mi = 0; mi < 8; mi++) {
    size_t row0 = rowBase + mi * 16 + lq * 4;
#pragma unroll
    for (int nf = 0; nf < 4; nf++) {
      int col = colBase + nf * 16 + lr;
#pragma unroll
      for (int j = 0; j < 4; j++) {
        float e = __expf(acc[mi][nf][j] * scale);
        C[(row0 + j) * 8192 + col] = f2bf(e);
        rs[mi][j] += e;
      }
    }
  }
#pragma unroll
  for (int mi = 0; mi < 8; mi++)
#pragma unroll
    for (int j = 0; j < 4; j++) {
      float r = rs[mi][j];
      r += __shfl_xor(r, 1); r += __shfl_xor(r, 2);
      r += __shfl_xor(r, 4); r += __shfl_xor(r, 8);
      if (lr == 0) atomicAdd(&rowsum[rowBase + mi * 16 + lq * 4 + j], r);
    }
}

// ---------------- bt-GEMM (m97 128^2 structure) for qkv / PV / proj ----------------
// MODE 0: bf16 out * scale
// MODE 2: f32 out + bias[col]
// MODE 3: bf16; tiles with tm>=128 (vn rows) write TRANSPOSED into Cv1 as vnT[col][row-16384]
//         (MFMA C/D layout: each lane holds 4 consecutive rows at one col -> one 8B store)
template <int MODE>
__global__ __launch_bounds__(256, 2) void gemm_bt(
    const u16* __restrict__ A0, const u16* __restrict__ B0,
    void* __restrict__ Cv0, void* __restrict__ Cv1,
    int M, int N, int K, int lda, int ldb, int ldc,
    float scale, const float* __restrict__ bias, size_t cSplitStride) {
  __shared__ __align__(16) u16 sA[128 * 64];
  __shared__ __align__(16) u16 sB[128 * 64];
  const int z = blockIdx.y;
  const u16* A = A0 + (size_t)z * (size_t)K;
  const u16* B = B0 + (size_t)z * (size_t)K;
  u16* Cb = (z < 2) ? ((u16*)Cv0 + (size_t)z * cSplitStride)
                    : ((u16*)Cv1 + (size_t)(z - 2) * cSplitStride);
  const int nTn = N >> 7;
  int nwg = gridDim.x, orig = blockIdx.x;
  int qq = nwg >> 3, rr = nwg & 7;
  int xcd = orig & 7, loc = orig >> 3;
  int wg = (xcd < rr ? xcd * (qq + 1) : rr * (qq + 1) + (xcd - rr) * qq) + loc;
  int tm = wg / nTn, tn = wg % nTn;

  const int t = threadIdx.x, l = t & 63, w = t >> 6;
  const int wr = w >> 1, wc = w & 1;
  const int lr = l & 15, kg = (l >> 4) << 3;

  f32x4 acc[4][4];
#pragma unroll
  for (int m = 0; m < 4; m++)
#pragma unroll
    for (int n = 0; n < 4; n++) acc[m][n] = (f32x4){0.f, 0.f, 0.f, 0.f};

  const size_t rowA0 = (size_t)tm * 128;
  const size_t rowB0 = (size_t)tn * 128;
  const int nk = K >> 6;
  for (int kt = 0; kt < nk; kt++) {
    const int k0 = kt << 6;
#pragma unroll
    for (int i = 0; i < 4; i++) {
      int chunk = i * 256 + t;
      int row = chunk >> 3;
      int col = (chunk & 7) << 3;
      gload_lds16(A + (rowA0 + row) * lda + k0 + col, (const char*)sA + (i * 256 + w * 64) * 16);
      gload_lds16(B + (rowB0 + row) * ldb + k0 + col, (const char*)sB + (i * 256 + w * 64) * 16);
    }
    __syncthreads();
#pragma unroll
    for (int kk = 0; kk < 2; kk++) {
      bf16x8 af[4], bfv[4];
#pragma unroll
      for (int m = 0; m < 4; m++)
        af[m] = *(const bf16x8*)&sA[(wr * 64 + m * 16 + lr) * 64 + kk * 32 + kg];
#pragma unroll
      for (int n = 0; n < 4; n++)
        bfv[n] = *(const bf16x8*)&sB[(wc * 64 + n * 16 + lr) * 64 + kk * 32 + kg];
#pragma unroll
      for (int m = 0; m < 4; m++)
#pragma unroll
        for (int n = 0; n < 4; n++)
          acc[m][n] = __builtin_amdgcn_mfma_f32_16x16x32_bf16(af[m], bfv[n], acc[m][n], 0, 0, 0);
    }
    __syncthreads();
  }
#pragma unroll
  for (int m = 0; m < 4; m++) {
    int row = tm * 128 + wr * 64 + m * 16 + ((l >> 4) << 2);
#pragma unroll
    for (int n = 0; n < 4; n++) {
      int col = tn * 128 + wc * 64 + n * 16 + lr;
      if (MODE == 2) {
#pragma unroll
        for (int j = 0; j < 4; j++)
          ((float*)Cv0)[(size_t)(row + j) * ldc + col] = acc[m][n][j] + bias[col];
      } else if (MODE == 3 && tm >= 128) {
        // vn tile -> write transposed: vnT[col][row-16384], 4 consecutive rows = 8B store
        ushort4 o;
        o.x = f2bf(acc[m][n][0]); o.y = f2bf(acc[m][n][1]);
        o.z = f2bf(acc[m][n][2]); o.w = f2bf(acc[m][n][3]);
        *(ushort4*)((u16*)Cv1 + (size_t)col * 8192 + (row - 16384)) = o;
      } else {
#pragma unroll
        for (int j = 0; j < 4; j++)
          Cb[(size_t)(row + j) * ldc + col] = f2bf(acc[m][n][j] * scale);
      }
    }
  }
}

// ---------------- host ----------------
extern "C" void kernel_launch(void* const* d_in, const int* in_sizes, int n_in,
                              void* d_out, int out_size, void* d_ws, size_t ws_size,
                              hipStream_t stream) {
  const float* q  = (const float*)d_in[0];
  const float* k  = (const float*)d_in[1];
  const float* v  = (const float*)d_in[2];
  const float* lw = (const float*)d_in[3];
  const float* lb = (const float*)d_in[4];
  const float* Wq = (const float*)d_in[5];
  const float* Wp = (const float*)d_in[6];
  const float* bp = (const float*)d_in[7];

  char* ws = (char*)d_ws;
  size_t off = 0;
  auto alloc = [&](size_t b) { size_t o = off; off += (b + 255) & ~(size_t)255; return o; };
  size_t o_ln = alloc((size_t)24576 * 768 * 2);  // LN(q,k,v) bf16; later: rowsum | p0 | p1
  size_t o_pj = alloc((size_t)24576 * 768 * 2);  // qn,kn bf16 | vnT (written by qkv MODE 3)
  size_t o_wq = alloc((size_t)768 * 768 * 2);
  size_t o_wp = alloc((size_t)768 * 768 * 2);
  u16* lnbuf = (u16*)(ws + o_ln);
  u16* pj    = (u16*)(ws + o_pj);
  u16* wqb   = (u16*)(ws + o_wq);
  u16* wpb   = (u16*)(ws + o_wp);
  const size_t NS = (size_t)8192 * 768;
  // lnbuf region after qkv GEMM consumed it: rowsum (32KB) | p0 | p1
  float* rowsum = (float*)lnbuf;
  u16* p0 = lnbuf + NS;
  u16* p1 = lnbuf + 2 * NS;
  // pj region: qn | kn | vnT (vn slot holds the TRANSPOSED vn, written directly by qkv)
  u16* vnT = pj + 2 * NS;
  u16* p2 = (u16*)d_out;                   // partials 2,3 in d_out (overwritten by proj)
  u16* p3 = p2 + NS;
  size_t fixedEnd = off;
  u16* Sbuf = (u16*)(ws + fixedEnd);       // P' = exp(S*scale) bf16, 8192x8192

  const float scale = 0.03608439182435161f;  // 1/sqrt(768)

  ln_cast_kernel<<<dim3(24576), dim3(256), 0, stream>>>(q, k, v, lw, lb, lnbuf);
  cast_f32_bf16<<<dim3(576), dim3(256), 0, stream>>>(Wq, wqb, 147456);
  cast_f32_bf16<<<dim3(576), dim3(256), 0, stream>>>(Wp, wpb, 147456);

  // qn/kn -> pj rows [0,16384); vn -> written TRANSPOSED into vnT (MODE 3, saves transpose64)
  gemm_bt<3><<<dim3(1152), dim3(256), 0, stream>>>(lnbuf, wqb, (void*)pj, (void*)vnT,
      24576, 768, 768, 768, 768, 768, 1.0f, (const float*)nullptr, 0);

  // rowsum lives in lnbuf (dead after qkv read it); zero AFTER qkv, before QK
  zero_f32<<<dim3(32), dim3(256), 0, stream>>>(rowsum, 8192);

  // P' = exp(qn @ kn^T * scale), rowsum via atomics — round-9 QK kernel
  qk_exp_256<<<dim3(1024), dim3(512), 0, stream>>>(pj, pj + NS, Sbuf, rowsum, scale);

  // attn partials = P' @ vn, 4-way split-K
  gemm_bt<0><<<dim3(384, 4), dim3(256), 0, stream>>>(
      Sbuf, vnT, (void*)p0, (void*)p2,
      8192, 768, 2048, 8192, 8192, 768, 1.0f, (const float*)nullptr, NS);

  // attn_out = (p0+p1+p2+p3) / rowsum
  reduce4_scale<<<dim3(3072), dim3(256), 0, stream>>>(p0, p1, p2, p3, rowsum, p0, (int)(NS / 8));

  // out = attn_out @ W_proj^T + b_proj
  gemm_bt<2><<<dim3(384), dim3(256), 0, stream>>>(p0, wpb, d_out, d_out,
      8192, 768, 768, 768, 768, 768, 1.0f, bp, 0);
}

// Round 12
// 352.468 us; speedup vs baseline: 3.8028x; 1.0107x over previous
//
#include <hip/hip_runtime.h>
#include <hip/hip_bf16.h>
#include <stdint.h>

typedef short bf16x8 __attribute__((ext_vector_type(8)));   // 8 bf16 in 4 VGPRs
typedef float f32x4 __attribute__((ext_vector_type(4)));
typedef unsigned short u16;
typedef u16 u16x8 __attribute__((ext_vector_type(8)));

__device__ __forceinline__ u16 f2bf(float x) {
  __hip_bfloat16 h = __float2bfloat16(x);
  return *reinterpret_cast<u16*>(&h);
}
__device__ __forceinline__ float bf2f(u16 v) {
  unsigned u = (unsigned)v << 16;
  return *reinterpret_cast<float*>(&u);
}

// async global->LDS, 16B per lane. LDS dest is wave-uniform base + lane*16 (m104/m108).
__device__ __forceinline__ void gload_lds16(const void* g, const void* lds_base) {
  __builtin_amdgcn_global_load_lds(
      (const __attribute__((address_space(1))) unsigned int*)(uintptr_t)g,
      (__attribute__((address_space(3))) unsigned int*)(uintptr_t)lds_base,
      16, 0, 0);
}

#define BAR() __builtin_amdgcn_s_barrier()

// ---------------- LayerNorm + cast to bf16 (rows of q,k,v), float4-vectorized ----------------
__global__ __launch_bounds__(256) void ln_cast_kernel(
    const float* __restrict__ q, const float* __restrict__ k, const float* __restrict__ v,
    const float* __restrict__ lw, const float* __restrict__ lb, u16* __restrict__ out) {
  int row = blockIdx.x;
  const float* x;
  if (row < 8192) x = q + (size_t)row * 768;
  else if (row < 16384) x = k + (size_t)(row - 8192) * 768;
  else x = v + (size_t)(row - 16384) * 768;
  int t = threadIdx.x;
  __shared__ float red[4];
  __shared__ float red2[4];
  float4 a = (t < 192) ? ((const float4*)x)[t] : make_float4(0.f, 0.f, 0.f, 0.f);
  float s = a.x + a.y + a.z + a.w;
  for (int o = 32; o; o >>= 1) s += __shfl_down(s, o, 64);
  if ((t & 63) == 0) red[t >> 6] = s;
  __syncthreads();
  float mean = (red[0] + red[1] + red[2]) * (1.0f / 768.0f);
  float4 d = make_float4(a.x - mean, a.y - mean, a.z - mean, a.w - mean);
  float vs = (t < 192) ? (d.x * d.x + d.y * d.y + d.z * d.z + d.w * d.w) : 0.f;
  for (int o = 32; o; o >>= 1) vs += __shfl_down(vs, o, 64);
  if ((t & 63) == 0) red2[t >> 6] = vs;
  __syncthreads();
  float var = (red2[0] + red2[1] + red2[2]) * (1.0f / 768.0f);
  float rstd = rsqrtf(var + 1e-5f);
  if (t < 192) {
    float4 wv = ((const float4*)lw)[t];
    float4 bv = ((const float4*)lb)[t];
    ushort4 o;
    o.x = f2bf(d.x * rstd * wv.x + bv.x);
    o.y = f2bf(d.y * rstd * wv.y + bv.y);
    o.z = f2bf(d.z * rstd * wv.z + bv.z);
    o.w = f2bf(d.w * rstd * wv.w + bv.w);
    ((ushort4*)(out + (size_t)row * 768))[t] = o;
  }
}

// ---------------- fp32 -> bf16 cast (weights) ----------------
__global__ __launch_bounds__(256) void cast_f32_bf16(const float* __restrict__ in,
                                                     u16* __restrict__ out, int n4) {
  int i = blockIdx.x * 256 + threadIdx.x;
  if (i < n4) {
    float4 vv = ((const float4*)in)[i];
    ushort4 o;
    o.x = f2bf(vv.x); o.y = f2bf(vv.y); o.z = f2bf(vv.z); o.w = f2bf(vv.w);
    ((ushort4*)out)[i] = o;
  }
}

// ---------------- zero fp32 buffer ----------------
__global__ __launch_bounds__(256) void zero_f32(float* __restrict__ p, int n) {
  int i = blockIdx.x * 256 + threadIdx.x;
  if (i < n) p[i] = 0.0f;
}

// ---------------- sum 4 bf16 partials, scale by 1/rowsum, write bf16 ----------------
__global__ __launch_bounds__(256) void reduce4_scale(
    const u16* __restrict__ p0, const u16* __restrict__ p1,
    const u16* __restrict__ p2, const u16* __restrict__ p3,
    const float* __restrict__ rowsum, u16* __restrict__ out, int n8) {
  int i = blockIdx.x * 256 + threadIdx.x;
  if (i < n8) {
    float inv = 1.0f / rowsum[i / 96];
    u16x8 a = ((const u16x8*)p0)[i];
    u16x8 b = ((const u16x8*)p1)[i];
    u16x8 c = ((const u16x8*)p2)[i];
    u16x8 d = ((const u16x8*)p3)[i];
    u16x8 o;
#pragma unroll
    for (int j = 0; j < 8; j++)
      o[j] = f2bf((bf2f(a[j]) + bf2f(b[j]) + bf2f(c[j]) + bf2f(d[j])) * inv);
    ((u16x8*)out)[i] = o;
  }
}

// ========== QK^T + exp, 256x256 tile, BK=32, 4-deep rotation, SINGLE barrier/phase ==========
// Round-12 change: removed the mid-phase barrier. Phase = {ds_read buf[T&3] | stage T+3 |
// MFMA (compiler lgkm-gated) | vmcnt(8) | BAR}. Waves drift within a phase -> one wave's
// ds_reads overlap another's MFMA cluster (LDS pipe || matrix pipe).
// Hazards (re-proved): RAW — own vmcnt(8) at end of T-1 confirms tile T landed; end barrier
// publishes all waves' staging. WAR — stage at T targets buf[(T-1)&3]; its readers lgkm-
// completed before their T-1 MFMA, hence before the end-of-(T-1) barrier, hence before any
// wave's phase-T stage issues. Drift bounded to one phase by the single barrier.
// Do NOT force waves/EU via launch_bounds: acc[8][4] needs ~200 VGPR (round-10: spill, 8.5x).
__global__ __launch_bounds__(512, 2) void qk_exp_256(
    const u16* __restrict__ A, const u16* __restrict__ B, u16* __restrict__ C,
    float* __restrict__ rowsum, float scale) {
  __shared__ __align__(16) u16 lds[8 * 256 * 32];  // 128 KB: A bufs 0-3 | B bufs 0-3
  int orig = blockIdx.x;               // 1024 blocks, %8==0
  int xcd = orig & 7, i = orig >> 3;
  int tm = xcd * 4 + (i & 3), tn = i >> 2;
  const int t = threadIdx.x, l = t & 63, w = t >> 6;
  const int wr = w >> 2, wc = w & 3;   // 2 x 4 wave grid
  const int lr = l & 15, lq = l >> 4;
  const int colb = lq * 16;

  f32x4 acc[8][4];
#pragma unroll
  for (int m = 0; m < 8; m++)
#pragma unroll
    for (int n = 0; n < 4; n++) acc[m][n] = (f32x4){0.f, 0.f, 0.f, 0.f};

  const size_t rA0 = (size_t)tm * 256, rB0 = (size_t)tn * 256;

  // ---- hoisted addressing ----
  const char* gsrc[4];
  int ldsoff[4];
#pragma unroll
  for (int idx = 0; idx < 4; idx++) {
    const u16* src = (idx < 2) ? A : B;
    size_t r0 = (idx < 2) ? rA0 : rB0;
    int p = idx & 1;
    int x = p * 8192 + t * 16;
    int r = x >> 6;
    int cb = (x & 63) ^ (((r >> 1) & 3) << 4);
    gsrc[idx] = (const char*)(src + (r0 + r) * 768) + cb;
    ldsoff[idx] = ((idx < 2) ? 0 : 65536) + p * 8192 + w * 1024;
  }
  int offA[2][4], offB[4];
#pragma unroll
  for (int mh = 0; mh < 2; mh++)
#pragma unroll
    for (int mf = 0; mf < 4; mf++) {
      int row = wr * 128 + (mh * 4 + mf) * 16 + lr;
      int x = row * 64 + colb;
      offA[mh][mf] = x ^ (((row >> 1) & 3) << 4);
    }
#pragma unroll
  for (int nf = 0; nf < 4; nf++) {
    int row = wc * 64 + nf * 16 + lr;
    int x = row * 64 + colb;
    offB[nf] = 65536 + (x ^ (((row >> 1) & 3) << 4));
  }

#define SCALL(BUF, TT, IDX)                                                  \
  gload_lds16(gsrc[IDX] + (size_t)(TT) * 64,                                 \
              (const char*)lds + (BUF) * 16384 + ldsoff[IDX])

  auto LOADA = [&](bf16x8 (&aF)[4], int b, int mh) {
#pragma unroll
    for (int mf = 0; mf < 4; mf++)
      aF[mf] = *(const bf16x8*)((const char*)lds + b * 16384 + offA[mh][mf]);
  };
  auto LOADB = [&](bf16x8 (&bF)[4], int b) {
#pragma unroll
    for (int nf = 0; nf < 4; nf++)
      bF[nf] = *(const bf16x8*)((const char*)lds + b * 16384 + offB[nf]);
  };
  auto MM32 = [&](bf16x8 (&aF)[4], bf16x8 (&aG)[4], bf16x8 (&bF)[4]) {
    __builtin_amdgcn_s_setprio(1);
#pragma unroll
    for (int mf = 0; mf < 4; mf++)
#pragma unroll
      for (int nf = 0; nf < 4; nf++)
        acc[mf][nf] = __builtin_amdgcn_mfma_f32_16x16x32_bf16(
            aF[mf], bF[nf], acc[mf][nf], 0, 0, 0);
#pragma unroll
    for (int mf = 0; mf < 4; mf++)
#pragma unroll
      for (int nf = 0; nf < 4; nf++)
        acc[4 + mf][nf] = __builtin_amdgcn_mfma_f32_16x16x32_bf16(
            aG[mf], bF[nf], acc[4 + mf][nf], 0, 0, 0);
    __builtin_amdgcn_s_setprio(0);
  };

#define PHASE(CUR, SBUF, STAGET, DOSTAGE, VMN)                               \
  do {                                                                       \
    bf16x8 aF[4], aG[4], bF[4];                                              \
    LOADA(aF, CUR, 0);                                                       \
    LOADA(aG, CUR, 1);                                                       \
    LOADB(bF, CUR);                                                          \
    if (DOSTAGE) {                                                           \
      SCALL(SBUF, STAGET, 0); SCALL(SBUF, STAGET, 1);                        \
      SCALL(SBUF, STAGET, 2); SCALL(SBUF, STAGET, 3);                        \
    }                                                                        \
    MM32(aF, aG, bF);  /* compiler inserts lgkmcnt wait before first MFMA */ \
    if ((VMN) == 8) asm volatile("s_waitcnt vmcnt(8)" ::: "memory");         \
    else if ((VMN) == 4) asm volatile("s_waitcnt vmcnt(4)" ::: "memory");    \
    else if ((VMN) == 0) asm volatile("s_waitcnt vmcnt(0)" ::: "memory");    \
    BAR();                                                                   \
  } while (0)

  // ---- prologue: stage tiles 0,1,2; wait for tile 0 (8 loads stay in flight) ----
  SCALL(0, 0, 0); SCALL(0, 0, 1); SCALL(0, 0, 2); SCALL(0, 0, 3);
  SCALL(1, 1, 0); SCALL(1, 1, 1); SCALL(1, 1, 2); SCALL(1, 1, 3);
  SCALL(2, 2, 0); SCALL(2, 2, 1); SCALL(2, 2, 2); SCALL(2, 2, 3);
  asm volatile("s_waitcnt vmcnt(8)" ::: "memory");
  BAR();

  // ---- main loop: T in [0,20), stage T+3, steady vmcnt(8) ----
  for (int Tb = 0; Tb < 20; Tb += 4) {
    PHASE(0, 3, Tb + 3, 1, 8);
    PHASE(1, 0, Tb + 4, 1, 8);
    PHASE(2, 1, Tb + 5, 1, 8);
    PHASE(3, 2, Tb + 6, 1, 8);
  }
  // ---- peeled tail: T=20 (stage 23), 21, 22, 23 ----
  PHASE(0, 3, 23, 1, 8);
  PHASE(1, 0, 0, 0, 4);
  PHASE(2, 0, 0, 0, 0);
  PHASE(3, 0, 0, 0, -1);

#undef PHASE
#undef SCALL

  // ---- epilogue: exp + store + per-row sums (C/D layout: col=lane&15, row=(lane>>4)*4+j) ----
  float rs[8][4];
#pragma unroll
  for (int m = 0; m < 8; m++)
#pragma unroll
    for (int j = 0; j < 4; j++) rs[m][j] = 0.0f;
  const size_t rowBase = rA0 + (size_t)wr * 128;
  const int colBase = tn * 256 + wc * 64;
#pragma unroll
  for (int mi = 0; mi < 8; mi++) {
    size_t row0 = rowBase + mi * 16 + lq * 4;
#pragma unroll
    for (int nf = 0; nf < 4; nf++) {
      int col = colBase + nf * 16 + lr;
#pragma unroll
      for (int j = 0; j < 4; j++) {
        float e = __expf(acc[mi][nf][j] * scale);
        C[(row0 + j) * 8192 + col] = f2bf(e);
        rs[mi][j] += e;
      }
    }
  }
#pragma unroll
  for (int mi = 0; mi < 8; mi++)
#pragma unroll
    for (int j = 0; j < 4; j++) {
      float r = rs[mi][j];
      r += __shfl_xor(r, 1); r += __shfl_xor(r, 2);
      r += __shfl_xor(r, 4); r += __shfl_xor(r, 8);
      if (lr == 0) atomicAdd(&rowsum[rowBase + mi * 16 + lq * 4 + j], r);
    }
}

// ---------------- bt-GEMM (m97 128^2 structure) for qkv / PV / proj ----------------
// MODE 0: bf16 out * scale
// MODE 2: f32 out + bias[col]
// MODE 3: bf16; tiles with tm>=128 (vn rows) write TRANSPOSED into Cv1 as vnT[col][row-16384]
template <int MODE>
__global__ __launch_bounds__(256, 2) void gemm_bt(
    const u16* __restrict__ A0, const u16* __restrict__ B0,
    void* __restrict__ Cv0, void* __restrict__ Cv1,
    int M, int N, int K, int lda, int ldb, int ldc,
    float scale, const float* __restrict__ bias, size_t cSplitStride) {
  __shared__ __align__(16) u16 sA[128 * 64];
  __shared__ __align__(16) u16 sB[128 * 64];
  const int z = blockIdx.y;
  const u16* A = A0 + (size_t)z * (size_t)K;
  const u16* B = B0 + (size_t)z * (size_t)K;
  u16* Cb = (z < 2) ? ((u16*)Cv0 + (size_t)z * cSplitStride)
                    : ((u16*)Cv1 + (size_t)(z - 2) * cSplitStride);
  const int nTn = N >> 7;
  int nwg = gridDim.x, orig = blockIdx.x;
  int qq = nwg >> 3, rr = nwg & 7;
  int xcd = orig & 7, loc = orig >> 3;
  int wg = (xcd < rr ? xcd * (qq + 1) : rr * (qq + 1) + (xcd - rr) * qq) + loc;
  int tm = wg / nTn, tn = wg % nTn;

  const int t = threadIdx.x, l = t & 63, w = t >> 6;
  const int wr = w >> 1, wc = w & 1;
  const int lr = l & 15, kg = (l >> 4) << 3;

  f32x4 acc[4][4];
#pragma unroll
  for (int m = 0; m < 4; m++)
#pragma unroll
    for (int n = 0; n < 4; n++) acc[m][n] = (f32x4){0.f, 0.f, 0.f, 0.f};

  const size_t rowA0 = (size_t)tm * 128;
  const size_t rowB0 = (size_t)tn * 128;
  const int nk = K >> 6;
  for (int kt = 0; kt < nk; kt++) {
    const int k0 = kt << 6;
#pragma unroll
    for (int i = 0; i < 4; i++) {
      int chunk = i * 256 + t;
      int row = chunk >> 3;
      int col = (chunk & 7) << 3;
      gload_lds16(A + (rowA0 + row) * lda + k0 + col, (const char*)sA + (i * 256 + w * 64) * 16);
      gload_lds16(B + (rowB0 + row) * ldb + k0 + col, (const char*)sB + (i * 256 + w * 64) * 16);
    }
    __syncthreads();
#pragma unroll
    for (int kk = 0; kk < 2; kk++) {
      bf16x8 af[4], bfv[4];
#pragma unroll
      for (int m = 0; m < 4; m++)
        af[m] = *(const bf16x8*)&sA[(wr * 64 + m * 16 + lr) * 64 + kk * 32 + kg];
#pragma unroll
      for (int n = 0; n < 4; n++)
        bfv[n] = *(const bf16x8*)&sB[(wc * 64 + n * 16 + lr) * 64 + kk * 32 + kg];
#pragma unroll
      for (int m = 0; m < 4; m++)
#pragma unroll
        for (int n = 0; n < 4; n++)
          acc[m][n] = __builtin_amdgcn_mfma_f32_16x16x32_bf16(af[m], bfv[n], acc[m][n], 0, 0, 0);
    }
    __syncthreads();
  }
#pragma unroll
  for (int m = 0; m < 4; m++) {
    int row = tm * 128 + wr * 64 + m * 16 + ((l >> 4) << 2);
#pragma unroll
    for (int n = 0; n < 4; n++) {
      int col = tn * 128 + wc * 64 + n * 16 + lr;
      if (MODE == 2) {
#pragma unroll
        for (int j = 0; j < 4; j++)
          ((float*)Cv0)[(size_t)(row + j) * ldc + col] = acc[m][n][j] + bias[col];
      } else if (MODE == 3 && tm >= 128) {
        ushort4 o;
        o.x = f2bf(acc[m][n][0]); o.y = f2bf(acc[m][n][1]);
        o.z = f2bf(acc[m][n][2]); o.w = f2bf(acc[m][n][3]);
        *(ushort4*)((u16*)Cv1 + (size_t)col * 8192 + (row - 16384)) = o;
      } else {
#pragma unroll
        for (int j = 0; j < 4; j++)
          Cb[(size_t)(row + j) * ldc + col] = f2bf(acc[m][n][j] * scale);
      }
    }
  }
}

// ---------------- host ----------------
extern "C" void kernel_launch(void* const* d_in, const int* in_sizes, int n_in,
                              void* d_out, int out_size, void* d_ws, size_t ws_size,
                              hipStream_t stream) {
  const float* q  = (const float*)d_in[0];
  const float* k  = (const float*)d_in[1];
  const float* v  = (const float*)d_in[2];
  const float* lw = (const float*)d_in[3];
  const float* lb = (const float*)d_in[4];
  const float* Wq = (const float*)d_in[5];
  const float* Wp = (const float*)d_in[6];
  const float* bp = (const float*)d_in[7];

  char* ws = (char*)d_ws;
  size_t off = 0;
  auto alloc = [&](size_t b) { size_t o = off; off += (b + 255) & ~(size_t)255; return o; };
  size_t o_ln = alloc((size_t)24576 * 768 * 2);  // LN(q,k,v) bf16; later: rowsum | p0 | p1
  size_t o_pj = alloc((size_t)24576 * 768 * 2);  // qn,kn bf16 | vnT (written by qkv MODE 3)
  size_t o_wq = alloc((size_t)768 * 768 * 2);
  size_t o_wp = alloc((size_t)768 * 768 * 2);
  u16* lnbuf = (u16*)(ws + o_ln);
  u16* pj    = (u16*)(ws + o_pj);
  u16* wqb   = (u16*)(ws + o_wq);
  u16* wpb   = (u16*)(ws + o_wp);
  const size_t NS = (size_t)8192 * 768;
  float* rowsum = (float*)lnbuf;           // lnbuf dead after qkv reads it
  u16* p0 = lnbuf + NS;
  u16* p1 = lnbuf + 2 * NS;
  u16* vnT = pj + 2 * NS;                  // vn slot holds TRANSPOSED vn (qkv MODE 3)
  u16* p2 = (u16*)d_out;                   // partials 2,3 in d_out (overwritten by proj)
  u16* p3 = p2 + NS;
  size_t fixedEnd = off;
  u16* Sbuf = (u16*)(ws + fixedEnd);       // P' = exp(S*scale) bf16, 8192x8192

  const float scale = 0.03608439182435161f;  // 1/sqrt(768)

  ln_cast_kernel<<<dim3(24576), dim3(256), 0, stream>>>(q, k, v, lw, lb, lnbuf);
  cast_f32_bf16<<<dim3(576), dim3(256), 0, stream>>>(Wq, wqb, 147456);
  cast_f32_bf16<<<dim3(576), dim3(256), 0, stream>>>(Wp, wpb, 147456);

  // qn/kn -> pj rows [0,16384); vn -> written TRANSPOSED into vnT (MODE 3)
  gemm_bt<3><<<dim3(1152), dim3(256), 0, stream>>>(lnbuf, wqb, (void*)pj, (void*)vnT,
      24576, 768, 768, 768, 768, 768, 1.0f, (const float*)nullptr, 0);

  zero_f32<<<dim3(32), dim3(256), 0, stream>>>(rowsum, 8192);

  // P' = exp(qn @ kn^T * scale), rowsum via atomics — single-barrier-per-phase kernel
  qk_exp_256<<<dim3(1024), dim3(512), 0, stream>>>(pj, pj + NS, Sbuf, rowsum, scale);

  // attn partials = P' @ vn, 4-way split-K
  gemm_bt<0><<<dim3(384, 4), dim3(256), 0, stream>>>(
      Sbuf, vnT, (void*)p0, (void*)p2,
      8192, 768, 2048, 8192, 8192, 768, 1.0f, (const float*)nullptr, NS);

  // attn_out = (p0+p1+p2+p3) / rowsum
  reduce4_scale<<<dim3(3072), dim3(256), 0, stream>>>(p0, p1, p2, p3, rowsum, p0, (int)(NS / 8));

  // out = attn_out @ W_proj^T + b_proj
  gemm_bt<2><<<dim3(384), dim3(256), 0, stream>>>(p0, wpb, d_out, d_out,
      8192, 768, 768, 768, 768, 768, 1.0f, bp, 0);
}

// Round 13
// 342.069 us; speedup vs baseline: 3.9184x; 1.0304x over previous
//
#include <hip/hip_runtime.h>
#include <hip/hip_bf16.h>
#include <stdint.h>

typedef short bf16x8 __attribute__((ext_vector_type(8)));   // 8 bf16 in 4 VGPRs
typedef float f32x4 __attribute__((ext_vector_type(4)));
typedef unsigned short u16;
typedef u16 u16x8 __attribute__((ext_vector_type(8)));

__device__ __forceinline__ u16 f2bf(float x) {
  __hip_bfloat16 h = __float2bfloat16(x);
  return *reinterpret_cast<u16*>(&h);
}
__device__ __forceinline__ float bf2f(u16 v) {
  unsigned u = (unsigned)v << 16;
  return *reinterpret_cast<float*>(&u);
}

// async global->LDS, 16B per lane. LDS dest is wave-uniform base + lane*16 (m104/m108).
__device__ __forceinline__ void gload_lds16(const void* g, const void* lds_base) {
  __builtin_amdgcn_global_load_lds(
      (const __attribute__((address_space(1))) unsigned int*)(uintptr_t)g,
      (__attribute__((address_space(3))) unsigned int*)(uintptr_t)lds_base,
      16, 0, 0);
}

#define BAR() __builtin_amdgcn_s_barrier()

// ---------------- LayerNorm + cast to bf16 (rows of q,k,v), float4-vectorized ----------------
__global__ __launch_bounds__(256) void ln_cast_kernel(
    const float* __restrict__ q, const float* __restrict__ k, const float* __restrict__ v,
    const float* __restrict__ lw, const float* __restrict__ lb, u16* __restrict__ out) {
  int row = blockIdx.x;
  const float* x;
  if (row < 8192) x = q + (size_t)row * 768;
  else if (row < 16384) x = k + (size_t)(row - 8192) * 768;
  else x = v + (size_t)(row - 16384) * 768;
  int t = threadIdx.x;
  __shared__ float red[4];
  __shared__ float red2[4];
  float4 a = (t < 192) ? ((const float4*)x)[t] : make_float4(0.f, 0.f, 0.f, 0.f);
  float s = a.x + a.y + a.z + a.w;
  for (int o = 32; o; o >>= 1) s += __shfl_down(s, o, 64);
  if ((t & 63) == 0) red[t >> 6] = s;
  __syncthreads();
  float mean = (red[0] + red[1] + red[2]) * (1.0f / 768.0f);
  float4 d = make_float4(a.x - mean, a.y - mean, a.z - mean, a.w - mean);
  float vs = (t < 192) ? (d.x * d.x + d.y * d.y + d.z * d.z + d.w * d.w) : 0.f;
  for (int o = 32; o; o >>= 1) vs += __shfl_down(vs, o, 64);
  if ((t & 63) == 0) red2[t >> 6] = vs;
  __syncthreads();
  float var = (red2[0] + red2[1] + red2[2]) * (1.0f / 768.0f);
  float rstd = rsqrtf(var + 1e-5f);
  if (t < 192) {
    float4 wv = ((const float4*)lw)[t];
    float4 bv = ((const float4*)lb)[t];
    ushort4 o;
    o.x = f2bf(d.x * rstd * wv.x + bv.x);
    o.y = f2bf(d.y * rstd * wv.y + bv.y);
    o.z = f2bf(d.z * rstd * wv.z + bv.z);
    o.w = f2bf(d.w * rstd * wv.w + bv.w);
    ((ushort4*)(out + (size_t)row * 768))[t] = o;
  }
}

// ---------------- both weight casts in one launch (blocks 0-575: Wq, 576-1151: Wp) ----------------
__global__ __launch_bounds__(256) void cast2_f32_bf16(
    const float* __restrict__ wa, const float* __restrict__ wb,
    u16* __restrict__ oa, u16* __restrict__ ob) {
  int i = blockIdx.x * 256 + threadIdx.x;
  const float* in = (i < 147456) ? wa : wb;
  u16* out = (i < 147456) ? oa : ob;
  int j = (i < 147456) ? i : i - 147456;
  float4 vv = ((const float4*)in)[j];
  ushort4 o;
  o.x = f2bf(vv.x); o.y = f2bf(vv.y); o.z = f2bf(vv.z); o.w = f2bf(vv.w);
  ((ushort4*)out)[j] = o;
}

// ---------------- zero fp32 buffer ----------------
__global__ __launch_bounds__(256) void zero_f32(float* __restrict__ p, int n) {
  int i = blockIdx.x * 256 + threadIdx.x;
  if (i < n) p[i] = 0.0f;
}

// ---------------- sum 4 bf16 partials, scale by 1/rowsum, write bf16 ----------------
__global__ __launch_bounds__(256) void reduce4_scale(
    const u16* __restrict__ p0, const u16* __restrict__ p1,
    const u16* __restrict__ p2, const u16* __restrict__ p3,
    const float* __restrict__ rowsum, u16* __restrict__ out, int n8) {
  int i = blockIdx.x * 256 + threadIdx.x;
  if (i < n8) {
    float inv = 1.0f / rowsum[i / 96];
    u16x8 a = ((const u16x8*)p0)[i];
    u16x8 b = ((const u16x8*)p1)[i];
    u16x8 c = ((const u16x8*)p2)[i];
    u16x8 d = ((const u16x8*)p3)[i];
    u16x8 o;
#pragma unroll
    for (int j = 0; j < 8; j++)
      o[j] = f2bf((bf2f(a[j]) + bf2f(b[j]) + bf2f(c[j]) + bf2f(d[j])) * inv);
    ((u16x8*)out)[i] = o;
  }
}

// ========== QK^T + exp, 256x256 tile, BK=32, 4-deep rotation, SINGLE barrier/phase ==========
// Proven round-12 kernel (145.3us): reads at phase start, stage T+3, one MFMA cluster,
// vmcnt(8), single end barrier. Do NOT force waves/EU (round-10: spill, 8.5x).
__global__ __launch_bounds__(512, 2) void qk_exp_256(
    const u16* __restrict__ A, const u16* __restrict__ B, u16* __restrict__ C,
    float* __restrict__ rowsum, float scale) {
  __shared__ __align__(16) u16 lds[8 * 256 * 32];  // 128 KB: A bufs 0-3 | B bufs 0-3
  int orig = blockIdx.x;               // 1024 blocks, %8==0
  int xcd = orig & 7, i = orig >> 3;
  int tm = xcd * 4 + (i & 3), tn = i >> 2;
  const int t = threadIdx.x, l = t & 63, w = t >> 6;
  const int wr = w >> 2, wc = w & 3;   // 2 x 4 wave grid
  const int lr = l & 15, lq = l >> 4;
  const int colb = lq * 16;

  f32x4 acc[8][4];
#pragma unroll
  for (int m = 0; m < 8; m++)
#pragma unroll
    for (int n = 0; n < 4; n++) acc[m][n] = (f32x4){0.f, 0.f, 0.f, 0.f};

  const size_t rA0 = (size_t)tm * 256, rB0 = (size_t)tn * 256;

  const char* gsrc[4];
  int ldsoff[4];
#pragma unroll
  for (int idx = 0; idx < 4; idx++) {
    const u16* src = (idx < 2) ? A : B;
    size_t r0 = (idx < 2) ? rA0 : rB0;
    int p = idx & 1;
    int x = p * 8192 + t * 16;
    int r = x >> 6;
    int cb = (x & 63) ^ (((r >> 1) & 3) << 4);
    gsrc[idx] = (const char*)(src + (r0 + r) * 768) + cb;
    ldsoff[idx] = ((idx < 2) ? 0 : 65536) + p * 8192 + w * 1024;
  }
  int offA[2][4], offB[4];
#pragma unroll
  for (int mh = 0; mh < 2; mh++)
#pragma unroll
    for (int mf = 0; mf < 4; mf++) {
      int row = wr * 128 + (mh * 4 + mf) * 16 + lr;
      int x = row * 64 + colb;
      offA[mh][mf] = x ^ (((row >> 1) & 3) << 4);
    }
#pragma unroll
  for (int nf = 0; nf < 4; nf++) {
    int row = wc * 64 + nf * 16 + lr;
    int x = row * 64 + colb;
    offB[nf] = 65536 + (x ^ (((row >> 1) & 3) << 4));
  }

#define SCALL(BUF, TT, IDX)                                                  \
  gload_lds16(gsrc[IDX] + (size_t)(TT) * 64,                                 \
              (const char*)lds + (BUF) * 16384 + ldsoff[IDX])

  auto LOADA = [&](bf16x8 (&aF)[4], int b, int mh) {
#pragma unroll
    for (int mf = 0; mf < 4; mf++)
      aF[mf] = *(const bf16x8*)((const char*)lds + b * 16384 + offA[mh][mf]);
  };
  auto LOADB = [&](bf16x8 (&bF)[4], int b) {
#pragma unroll
    for (int nf = 0; nf < 4; nf++)
      bF[nf] = *(const bf16x8*)((const char*)lds + b * 16384 + offB[nf]);
  };
  auto MM32 = [&](bf16x8 (&aF)[4], bf16x8 (&aG)[4], bf16x8 (&bF)[4]) {
    __builtin_amdgcn_s_setprio(1);
#pragma unroll
    for (int mf = 0; mf < 4; mf++)
#pragma unroll
      for (int nf = 0; nf < 4; nf++)
        acc[mf][nf] = __builtin_amdgcn_mfma_f32_16x16x32_bf16(
            aF[mf], bF[nf], acc[mf][nf], 0, 0, 0);
#pragma unroll
    for (int mf = 0; mf < 4; mf++)
#pragma unroll
      for (int nf = 0; nf < 4; nf++)
        acc[4 + mf][nf] = __builtin_amdgcn_mfma_f32_16x16x32_bf16(
            aG[mf], bF[nf], acc[4 + mf][nf], 0, 0, 0);
    __builtin_amdgcn_s_setprio(0);
  };

#define PHASE(CUR, SBUF, STAGET, DOSTAGE, VMN)                               \
  do {                                                                       \
    bf16x8 aF[4], aG[4], bF[4];                                              \
    LOADA(aF, CUR, 0);                                                       \
    LOADA(aG, CUR, 1);                                                       \
    LOADB(bF, CUR);                                                          \
    if (DOSTAGE) {                                                           \
      SCALL(SBUF, STAGET, 0); SCALL(SBUF, STAGET, 1);                        \
      SCALL(SBUF, STAGET, 2); SCALL(SBUF, STAGET, 3);                        \
    }                                                                        \
    MM32(aF, aG, bF);                                                        \
    if ((VMN) == 8) asm volatile("s_waitcnt vmcnt(8)" ::: "memory");         \
    else if ((VMN) == 4) asm volatile("s_waitcnt vmcnt(4)" ::: "memory");    \
    else if ((VMN) == 0) asm volatile("s_waitcnt vmcnt(0)" ::: "memory");    \
    BAR();                                                                   \
  } while (0)

  SCALL(0, 0, 0); SCALL(0, 0, 1); SCALL(0, 0, 2); SCALL(0, 0, 3);
  SCALL(1, 1, 0); SCALL(1, 1, 1); SCALL(1, 1, 2); SCALL(1, 1, 3);
  SCALL(2, 2, 0); SCALL(2, 2, 1); SCALL(2, 2, 2); SCALL(2, 2, 3);
  asm volatile("s_waitcnt vmcnt(8)" ::: "memory");
  BAR();

  for (int Tb = 0; Tb < 20; Tb += 4) {
    PHASE(0, 3, Tb + 3, 1, 8);
    PHASE(1, 0, Tb + 4, 1, 8);
    PHASE(2, 1, Tb + 5, 1, 8);
    PHASE(3, 2, Tb + 6, 1, 8);
  }
  PHASE(0, 3, 23, 1, 8);
  PHASE(1, 0, 0, 0, 4);
  PHASE(2, 0, 0, 0, 0);
  PHASE(3, 0, 0, 0, -1);

#undef PHASE
#undef SCALL

  float rs[8][4];
#pragma unroll
  for (int m = 0; m < 8; m++)
#pragma unroll
    for (int j = 0; j < 4; j++) rs[m][j] = 0.0f;
  const size_t rowBase = rA0 + (size_t)wr * 128;
  const int colBase = tn * 256 + wc * 64;
#pragma unroll
  for (int mi = 0; mi < 8; mi++) {
    size_t row0 = rowBase + mi * 16 + lq * 4;
#pragma unroll
    for (int nf = 0; nf < 4; nf++) {
      int col = colBase + nf * 16 + lr;
#pragma unroll
      for (int j = 0; j < 4; j++) {
        float e = __expf(acc[mi][nf][j] * scale);
        C[(row0 + j) * 8192 + col] = f2bf(e);
        rs[mi][j] += e;
      }
    }
  }
#pragma unroll
  for (int mi = 0; mi < 8; mi++)
#pragma unroll
    for (int j = 0; j < 4; j++) {
      float r = rs[mi][j];
      r += __shfl_xor(r, 1); r += __shfl_xor(r, 2);
      r += __shfl_xor(r, 4); r += __shfl_xor(r, 8);
      if (lr == 0) atomicAdd(&rowsum[rowBase + mi * 16 + lq * 4 + j], r);
    }
}

// ========== PV: partial_z = P'[:, z*2048:(z+1)*2048] @ vnT[:, same]^T  ==========
// 128x128 tile, 256 thr (4 waves 2x2, 64x64 each), BK=32, 4-buf rotation, stage-ahead-3,
// counted vmcnt(8), single barrier/phase — the round-12-proven schedule at 64KB LDS ->
// 2 blocks/CU co-resident (m114 overlap) + counted-vmcnt prefetch. grid (384, 4).
__global__ __launch_bounds__(256, 2) void pv_128(
    const u16* __restrict__ A, const u16* __restrict__ B,
    u16* __restrict__ C0, u16* __restrict__ C1) {
  __shared__ __align__(16) u16 lds[4 * 8192];  // 64 KB: A bufs 0-3 (32KB) | B bufs 0-3 (32KB)
  const int z = blockIdx.y;
  const int KOFF = z << 11;                    // z*2048
  u16* C = (z < 2) ? C0 + (size_t)z * 6291456 : C1 + (size_t)(z - 2) * 6291456;
  int orig = blockIdx.x;                       // 384 blocks, %8==0 (48/XCD)
  int wg = (orig & 7) * 48 + (orig >> 3);
  int tm = wg / 6, tn = wg % 6;
  const int t = threadIdx.x, l = t & 63, w = t >> 6;
  const int wr = w >> 1, wc = w & 1;           // 2 x 2 wave grid
  const int lr = l & 15, lq = l >> 4;
  const int colb = lq * 16;

  f32x4 acc[4][4];
#pragma unroll
  for (int m = 0; m < 4; m++)
#pragma unroll
    for (int n = 0; n < 4; n++) acc[m][n] = (f32x4){0.f, 0.f, 0.f, 0.f};

  const size_t rA0 = (size_t)tm * 128, rB0 = (size_t)tn * 128;

  // hoisted addressing (idx: 0,1 = A row-halves; 2,3 = B row-halves)
  const char* gsrc[4];
  int ldsoff[4];
#pragma unroll
  for (int idx = 0; idx < 4; idx++) {
    const u16* src = (idx < 2) ? A : B;
    size_t r0 = (idx < 2) ? rA0 : rB0;
    int p = idx & 1;
    int x = p * 4096 + t * 16;                  // byte offset in 8KB tile
    int r = x >> 6;                             // row 0..127
    int cb = (x & 63) ^ (((r >> 1) & 3) << 4);  // pre-swizzled source byte col
    gsrc[idx] = (const char*)(src + (r0 + r) * 8192 + KOFF) + cb;
    ldsoff[idx] = ((idx < 2) ? 0 : 32768) + p * 4096 + w * 1024;
  }
  int offA[4], offB[4];
#pragma unroll
  for (int mf = 0; mf < 4; mf++) {
    int row = wr * 64 + mf * 16 + lr;
    int x = row * 64 + colb;
    offA[mf] = x ^ (((row >> 1) & 3) << 4);
  }
#pragma unroll
  for (int nf = 0; nf < 4; nf++) {
    int row = wc * 64 + nf * 16 + lr;
    int x = row * 64 + colb;
    offB[nf] = 32768 + (x ^ (((row >> 1) & 3) << 4));
  }

#define PSCALL(BUF, TT, IDX)                                                 \
  gload_lds16(gsrc[IDX] + (size_t)(TT) * 64,                                 \
              (const char*)lds + (BUF) * 8192 + ldsoff[IDX])

  // prologue: stage tiles 0,1,2; wait tile 0 (8 in flight); barrier
  PSCALL(0, 0, 0); PSCALL(0, 0, 1); PSCALL(0, 0, 2); PSCALL(0, 0, 3);
  PSCALL(1, 1, 0); PSCALL(1, 1, 1); PSCALL(1, 1, 2); PSCALL(1, 1, 3);
  PSCALL(2, 2, 0); PSCALL(2, 2, 1); PSCALL(2, 2, 2); PSCALL(2, 2, 3);
  asm volatile("s_waitcnt vmcnt(8)" ::: "memory");
  BAR();

#pragma unroll 4
  for (int T = 0; T < 64; T++) {
    const int cur = T & 3;
    bf16x8 aF[4], bF[4];
#pragma unroll
    for (int mf = 0; mf < 4; mf++)
      aF[mf] = *(const bf16x8*)((const char*)lds + cur * 8192 + offA[mf]);
#pragma unroll
    for (int nf = 0; nf < 4; nf++)
      bF[nf] = *(const bf16x8*)((const char*)lds + cur * 8192 + offB[nf]);
    if (T < 61) {
      const int nb = (T + 3) & 3;
      PSCALL(nb, T + 3, 0); PSCALL(nb, T + 3, 1);
      PSCALL(nb, T + 3, 2); PSCALL(nb, T + 3, 3);
    }
    __builtin_amdgcn_s_setprio(1);
#pragma unroll
    for (int mf = 0; mf < 4; mf++)
#pragma unroll
      for (int nf = 0; nf < 4; nf++)
        acc[mf][nf] = __builtin_amdgcn_mfma_f32_16x16x32_bf16(
            aF[mf], bF[nf], acc[mf][nf], 0, 0, 0);
    __builtin_amdgcn_s_setprio(0);
    if (T < 61)       asm volatile("s_waitcnt vmcnt(8)" ::: "memory");
    else if (T == 61) asm volatile("s_waitcnt vmcnt(4)" ::: "memory");
    else if (T == 62) asm volatile("s_waitcnt vmcnt(0)" ::: "memory");
    BAR();
  }
#undef PSCALL

  // epilogue: bf16 partial write (C/D layout col=lane&15, row=(lane>>4)*4+j)
#pragma unroll
  for (int mf = 0; mf < 4; mf++) {
    int row = tm * 128 + wr * 64 + mf * 16 + lq * 4;
#pragma unroll
    for (int nf = 0; nf < 4; nf++) {
      int col = tn * 128 + wc * 64 + nf * 16 + lr;
#pragma unroll
      for (int j = 0; j < 4; j++)
        C[(size_t)(row + j) * 768 + col] = f2bf(acc[mf][nf][j]);
    }
  }
}

// ---------------- bt-GEMM (m97 128^2 structure) for qkv / proj ----------------
// MODE 2: f32 out + bias[col]
// MODE 3: bf16; tiles with tm>=128 (vn rows) write TRANSPOSED into Cv1 as vnT[col][row-16384]
template <int MODE>
__global__ __launch_bounds__(256, 2) void gemm_bt(
    const u16* __restrict__ A0, const u16* __restrict__ B0,
    void* __restrict__ Cv0, void* __restrict__ Cv1,
    int M, int N, int K, int lda, int ldb, int ldc,
    float scale, const float* __restrict__ bias, size_t cSplitStride) {
  __shared__ __align__(16) u16 sA[128 * 64];
  __shared__ __align__(16) u16 sB[128 * 64];
  const int z = blockIdx.y;
  const u16* A = A0 + (size_t)z * (size_t)K;
  const u16* B = B0 + (size_t)z * (size_t)K;
  u16* Cb = (z < 2) ? ((u16*)Cv0 + (size_t)z * cSplitStride)
                    : ((u16*)Cv1 + (size_t)(z - 2) * cSplitStride);
  const int nTn = N >> 7;
  int nwg = gridDim.x, orig = blockIdx.x;
  int qq = nwg >> 3, rr = nwg & 7;
  int xcd = orig & 7, loc = orig >> 3;
  int wg = (xcd < rr ? xcd * (qq + 1) : rr * (qq + 1) + (xcd - rr) * qq) + loc;
  int tm = wg / nTn, tn = wg % nTn;

  const int t = threadIdx.x, l = t & 63, w = t >> 6;
  const int wr = w >> 1, wc = w & 1;
  const int lr = l & 15, kg = (l >> 4) << 3;

  f32x4 acc[4][4];
#pragma unroll
  for (int m = 0; m < 4; m++)
#pragma unroll
    for (int n = 0; n < 4; n++) acc[m][n] = (f32x4){0.f, 0.f, 0.f, 0.f};

  const size_t rowA0 = (size_t)tm * 128;
  const size_t rowB0 = (size_t)tn * 128;
  const int nk = K >> 6;
  for (int kt = 0; kt < nk; kt++) {
    const int k0 = kt << 6;
#pragma unroll
    for (int i = 0; i < 4; i++) {
      int chunk = i * 256 + t;
      int row = chunk >> 3;
      int col = (chunk & 7) << 3;
      gload_lds16(A + (rowA0 + row) * lda + k0 + col, (const char*)sA + (i * 256 + w * 64) * 16);
      gload_lds16(B + (rowB0 + row) * ldb + k0 + col, (const char*)sB + (i * 256 + w * 64) * 16);
    }
    __syncthreads();
#pragma unroll
    for (int kk = 0; kk < 2; kk++) {
      bf16x8 af[4], bfv[4];
#pragma unroll
      for (int m = 0; m < 4; m++)
        af[m] = *(const bf16x8*)&sA[(wr * 64 + m * 16 + lr) * 64 + kk * 32 + kg];
#pragma unroll
      for (int n = 0; n < 4; n++)
        bfv[n] = *(const bf16x8*)&sB[(wc * 64 + n * 16 + lr) * 64 + kk * 32 + kg];
#pragma unroll
      for (int m = 0; m < 4; m++)
#pragma unroll
        for (int n = 0; n < 4; n++)
          acc[m][n] = __builtin_amdgcn_mfma_f32_16x16x32_bf16(af[m], bfv[n], acc[m][n], 0, 0, 0);
    }
    __syncthreads();
  }
#pragma unroll
  for (int m = 0; m < 4; m++) {
    int row = tm * 128 + wr * 64 + m * 16 + ((l >> 4) << 2);
#pragma unroll
    for (int n = 0; n < 4; n++) {
      int col = tn * 128 + wc * 64 + n * 16 + lr;
      if (MODE == 2) {
#pragma unroll
        for (int j = 0; j < 4; j++)
          ((float*)Cv0)[(size_t)(row + j) * ldc + col] = acc[m][n][j] + bias[col];
      } else if (MODE == 3 && tm >= 128) {
        ushort4 o;
        o.x = f2bf(acc[m][n][0]); o.y = f2bf(acc[m][n][1]);
        o.z = f2bf(acc[m][n][2]); o.w = f2bf(acc[m][n][3]);
        *(ushort4*)((u16*)Cv1 + (size_t)col * 8192 + (row - 16384)) = o;
      } else {
#pragma unroll
        for (int j = 0; j < 4; j++)
          Cb[(size_t)(row + j) * ldc + col] = f2bf(acc[m][n][j] * scale);
      }
    }
  }
}

// ---------------- host ----------------
extern "C" void kernel_launch(void* const* d_in, const int* in_sizes, int n_in,
                              void* d_out, int out_size, void* d_ws, size_t ws_size,
                              hipStream_t stream) {
  const float* q  = (const float*)d_in[0];
  const float* k  = (const float*)d_in[1];
  const float* v  = (const float*)d_in[2];
  const float* lw = (const float*)d_in[3];
  const float* lb = (const float*)d_in[4];
  const float* Wq = (const float*)d_in[5];
  const float* Wp = (const float*)d_in[6];
  const float* bp = (const float*)d_in[7];

  char* ws = (char*)d_ws;
  size_t off = 0;
  auto alloc = [&](size_t b) { size_t o = off; off += (b + 255) & ~(size_t)255; return o; };
  size_t o_ln = alloc((size_t)24576 * 768 * 2);  // LN(q,k,v) bf16; later: rowsum | p0 | p1
  size_t o_pj = alloc((size_t)24576 * 768 * 2);  // qn,kn bf16 | vnT (written by qkv MODE 3)
  size_t o_wq = alloc((size_t)768 * 768 * 2);
  size_t o_wp = alloc((size_t)768 * 768 * 2);
  u16* lnbuf = (u16*)(ws + o_ln);
  u16* pj    = (u16*)(ws + o_pj);
  u16* wqb   = (u16*)(ws + o_wq);
  u16* wpb   = (u16*)(ws + o_wp);
  const size_t NS = (size_t)8192 * 768;
  float* rowsum = (float*)lnbuf;           // lnbuf dead after qkv reads it
  u16* p0 = lnbuf + NS;
  u16* p1 = lnbuf + 2 * NS;
  u16* vnT = pj + 2 * NS;                  // vn slot holds TRANSPOSED vn (qkv MODE 3)
  u16* p2 = (u16*)d_out;                   // partials 2,3 in d_out (overwritten by proj)
  u16* p3 = p2 + NS;
  size_t fixedEnd = off;
  u16* Sbuf = (u16*)(ws + fixedEnd);       // P' = exp(S*scale) bf16, 8192x8192

  const float scale = 0.03608439182435161f;  // 1/sqrt(768)

  ln_cast_kernel<<<dim3(24576), dim3(256), 0, stream>>>(q, k, v, lw, lb, lnbuf);
  cast2_f32_bf16<<<dim3(1152), dim3(256), 0, stream>>>(Wq, Wp, wqb, wpb);

  // qn/kn -> pj rows [0,16384); vn -> written TRANSPOSED into vnT (MODE 3)
  gemm_bt<3><<<dim3(1152), dim3(256), 0, stream>>>(lnbuf, wqb, (void*)pj, (void*)vnT,
      24576, 768, 768, 768, 768, 768, 1.0f, (const float*)nullptr, 0);

  zero_f32<<<dim3(32), dim3(256), 0, stream>>>(rowsum, 8192);

  // P' = exp(qn @ kn^T * scale), rowsum via atomics — single-barrier-per-phase kernel
  qk_exp_256<<<dim3(1024), dim3(512), 0, stream>>>(pj, pj + NS, Sbuf, rowsum, scale);

  // attn partials = P' @ vn, 4-way split-K — new counted-vmcnt PV kernel
  pv_128<<<dim3(384, 4), dim3(256), 0, stream>>>(Sbuf, vnT, p0, p2);

  // attn_out = (p0+p1+p2+p3) / rowsum
  reduce4_scale<<<dim3(3072), dim3(256), 0, stream>>>(p0, p1, p2, p3, rowsum, p0, (int)(NS / 8));

  // out = attn_out @ W_proj^T + b_proj
  gemm_bt<2><<<dim3(384), dim3(256), 0, stream>>>(p0, wpb, d_out, d_out,
      8192, 768, 768, 768, 768, 768, 1.0f, bp, 0);
}

// Round 14
// 338.956 us; speedup vs baseline: 3.9544x; 1.0092x over previous
//
#include <hip/hip_runtime.h>
#include <hip/hip_bf16.h>
#include <stdint.h>

typedef short bf16x8 __attribute__((ext_vector_type(8)));   // 8 bf16 in 4 VGPRs
typedef float f32x4 __attribute__((ext_vector_type(4)));
typedef unsigned short u16;
typedef u16 u16x8 __attribute__((ext_vector_type(8)));

__device__ __forceinline__ u16 f2bf(float x) {
  __hip_bfloat16 h = __float2bfloat16(x);
  return *reinterpret_cast<u16*>(&h);
}
__device__ __forceinline__ float bf2f(u16 v) {
  unsigned u = (unsigned)v << 16;
  return *reinterpret_cast<float*>(&u);
}

// async global->LDS, 16B per lane. LDS dest is wave-uniform base + lane*16 (m104/m108).
__device__ __forceinline__ void gload_lds16(const void* g, const void* lds_base) {
  __builtin_amdgcn_global_load_lds(
      (const __attribute__((address_space(1))) unsigned int*)(uintptr_t)g,
      (__attribute__((address_space(3))) unsigned int*)(uintptr_t)lds_base,
      16, 0, 0);
}

#define BAR() __builtin_amdgcn_s_barrier()

// ---------------- LayerNorm + cast to bf16 (rows of q,k,v), float4-vectorized ----------------
__global__ __launch_bounds__(256) void ln_cast_kernel(
    const float* __restrict__ q, const float* __restrict__ k, const float* __restrict__ v,
    const float* __restrict__ lw, const float* __restrict__ lb, u16* __restrict__ out) {
  int row = blockIdx.x;
  const float* x;
  if (row < 8192) x = q + (size_t)row * 768;
  else if (row < 16384) x = k + (size_t)(row - 8192) * 768;
  else x = v + (size_t)(row - 16384) * 768;
  int t = threadIdx.x;
  __shared__ float red[4];
  __shared__ float red2[4];
  float4 a = (t < 192) ? ((const float4*)x)[t] : make_float4(0.f, 0.f, 0.f, 0.f);
  float s = a.x + a.y + a.z + a.w;
  for (int o = 32; o; o >>= 1) s += __shfl_down(s, o, 64);
  if ((t & 63) == 0) red[t >> 6] = s;
  __syncthreads();
  float mean = (red[0] + red[1] + red[2]) * (1.0f / 768.0f);
  float4 d = make_float4(a.x - mean, a.y - mean, a.z - mean, a.w - mean);
  float vs = (t < 192) ? (d.x * d.x + d.y * d.y + d.z * d.z + d.w * d.w) : 0.f;
  for (int o = 32; o; o >>= 1) vs += __shfl_down(vs, o, 64);
  if ((t & 63) == 0) red2[t >> 6] = vs;
  __syncthreads();
  float var = (red2[0] + red2[1] + red2[2]) * (1.0f / 768.0f);
  float rstd = rsqrtf(var + 1e-5f);
  if (t < 192) {
    float4 wv = ((const float4*)lw)[t];
    float4 bv = ((const float4*)lb)[t];
    ushort4 o;
    o.x = f2bf(d.x * rstd * wv.x + bv.x);
    o.y = f2bf(d.y * rstd * wv.y + bv.y);
    o.z = f2bf(d.z * rstd * wv.z + bv.z);
    o.w = f2bf(d.w * rstd * wv.w + bv.w);
    ((ushort4*)(out + (size_t)row * 768))[t] = o;
  }
}

// ---------------- both weight casts in one launch ----------------
__global__ __launch_bounds__(256) void cast2_f32_bf16(
    const float* __restrict__ wa, const float* __restrict__ wb,
    u16* __restrict__ oa, u16* __restrict__ ob) {
  int i = blockIdx.x * 256 + threadIdx.x;
  const float* in = (i < 147456) ? wa : wb;
  u16* out = (i < 147456) ? oa : ob;
  int j = (i < 147456) ? i : i - 147456;
  float4 vv = ((const float4*)in)[j];
  ushort4 o;
  o.x = f2bf(vv.x); o.y = f2bf(vv.y); o.z = f2bf(vv.z); o.w = f2bf(vv.w);
  ((ushort4*)out)[j] = o;
}

// ---------------- zero fp32 buffer ----------------
__global__ __launch_bounds__(256) void zero_f32(float* __restrict__ p, int n) {
  int i = blockIdx.x * 256 + threadIdx.x;
  if (i < n) p[i] = 0.0f;
}

// ---------------- sum 4 bf16 partials, scale by 1/rowsum, write bf16 ----------------
__global__ __launch_bounds__(256) void reduce4_scale(
    const u16* __restrict__ p0, const u16* __restrict__ p1,
    const u16* __restrict__ p2, const u16* __restrict__ p3,
    const float* __restrict__ rowsum, u16* __restrict__ out, int n8) {
  int i = blockIdx.x * 256 + threadIdx.x;
  if (i < n8) {
    float inv = 1.0f / rowsum[i / 96];
    u16x8 a = ((const u16x8*)p0)[i];
    u16x8 b = ((const u16x8*)p1)[i];
    u16x8 c = ((const u16x8*)p2)[i];
    u16x8 d = ((const u16x8*)p3)[i];
    u16x8 o;
#pragma unroll
    for (int j = 0; j < 8; j++)
      o[j] = f2bf((bf2f(a[j]) + bf2f(b[j]) + bf2f(c[j]) + bf2f(d[j])) * inv);
    ((u16x8*)out)[i] = o;
  }
}

// ========== QK^T + exp, 256x256 tile, BK=32, 4-deep rotation, SINGLE barrier/phase ==========
// Proven round-12/13 kernel (145.3us). Do NOT force waves/EU (round-10: spill, 8.5x).
__global__ __launch_bounds__(512, 2) void qk_exp_256(
    const u16* __restrict__ A, const u16* __restrict__ B, u16* __restrict__ C,
    float* __restrict__ rowsum, float scale) {
  __shared__ __align__(16) u16 lds[8 * 256 * 32];  // 128 KB: A bufs 0-3 | B bufs 0-3
  int orig = blockIdx.x;               // 1024 blocks, %8==0
  int xcd = orig & 7, i = orig >> 3;
  int tm = xcd * 4 + (i & 3), tn = i >> 2;
  const int t = threadIdx.x, l = t & 63, w = t >> 6;
  const int wr = w >> 2, wc = w & 3;   // 2 x 4 wave grid
  const int lr = l & 15, lq = l >> 4;
  const int colb = lq * 16;

  f32x4 acc[8][4];
#pragma unroll
  for (int m = 0; m < 8; m++)
#pragma unroll
    for (int n = 0; n < 4; n++) acc[m][n] = (f32x4){0.f, 0.f, 0.f, 0.f};

  const size_t rA0 = (size_t)tm * 256, rB0 = (size_t)tn * 256;

  const char* gsrc[4];
  int ldsoff[4];
#pragma unroll
  for (int idx = 0; idx < 4; idx++) {
    const u16* src = (idx < 2) ? A : B;
    size_t r0 = (idx < 2) ? rA0 : rB0;
    int p = idx & 1;
    int x = p * 8192 + t * 16;
    int r = x >> 6;
    int cb = (x & 63) ^ (((r >> 1) & 3) << 4);
    gsrc[idx] = (const char*)(src + (r0 + r) * 768) + cb;
    ldsoff[idx] = ((idx < 2) ? 0 : 65536) + p * 8192 + w * 1024;
  }
  int offA[2][4], offB[4];
#pragma unroll
  for (int mh = 0; mh < 2; mh++)
#pragma unroll
    for (int mf = 0; mf < 4; mf++) {
      int row = wr * 128 + (mh * 4 + mf) * 16 + lr;
      int x = row * 64 + colb;
      offA[mh][mf] = x ^ (((row >> 1) & 3) << 4);
    }
#pragma unroll
  for (int nf = 0; nf < 4; nf++) {
    int row = wc * 64 + nf * 16 + lr;
    int x = row * 64 + colb;
    offB[nf] = 65536 + (x ^ (((row >> 1) & 3) << 4));
  }

#define SCALL(BUF, TT, IDX)                                                  \
  gload_lds16(gsrc[IDX] + (size_t)(TT) * 64,                                 \
              (const char*)lds + (BUF) * 16384 + ldsoff[IDX])

  auto LOADA = [&](bf16x8 (&aF)[4], int b, int mh) {
#pragma unroll
    for (int mf = 0; mf < 4; mf++)
      aF[mf] = *(const bf16x8*)((const char*)lds + b * 16384 + offA[mh][mf]);
  };
  auto LOADB = [&](bf16x8 (&bF)[4], int b) {
#pragma unroll
    for (int nf = 0; nf < 4; nf++)
      bF[nf] = *(const bf16x8*)((const char*)lds + b * 16384 + offB[nf]);
  };
  auto MM32 = [&](bf16x8 (&aF)[4], bf16x8 (&aG)[4], bf16x8 (&bF)[4]) {
    __builtin_amdgcn_s_setprio(1);
#pragma unroll
    for (int mf = 0; mf < 4; mf++)
#pragma unroll
      for (int nf = 0; nf < 4; nf++)
        acc[mf][nf] = __builtin_amdgcn_mfma_f32_16x16x32_bf16(
            aF[mf], bF[nf], acc[mf][nf], 0, 0, 0);
#pragma unroll
    for (int mf = 0; mf < 4; mf++)
#pragma unroll
      for (int nf = 0; nf < 4; nf++)
        acc[4 + mf][nf] = __builtin_amdgcn_mfma_f32_16x16x32_bf16(
            aG[mf], bF[nf], acc[4 + mf][nf], 0, 0, 0);
    __builtin_amdgcn_s_setprio(0);
  };

#define PHASE(CUR, SBUF, STAGET, DOSTAGE, VMN)                               \
  do {                                                                       \
    bf16x8 aF[4], aG[4], bF[4];                                              \
    LOADA(aF, CUR, 0);                                                       \
    LOADA(aG, CUR, 1);                                                       \
    LOADB(bF, CUR);                                                          \
    if (DOSTAGE) {                                                           \
      SCALL(SBUF, STAGET, 0); SCALL(SBUF, STAGET, 1);                        \
      SCALL(SBUF, STAGET, 2); SCALL(SBUF, STAGET, 3);                        \
    }                                                                        \
    MM32(aF, aG, bF);                                                        \
    if ((VMN) == 8) asm volatile("s_waitcnt vmcnt(8)" ::: "memory");         \
    else if ((VMN) == 4) asm volatile("s_waitcnt vmcnt(4)" ::: "memory");    \
    else if ((VMN) == 0) asm volatile("s_waitcnt vmcnt(0)" ::: "memory");    \
    BAR();                                                                   \
  } while (0)

  SCALL(0, 0, 0); SCALL(0, 0, 1); SCALL(0, 0, 2); SCALL(0, 0, 3);
  SCALL(1, 1, 0); SCALL(1, 1, 1); SCALL(1, 1, 2); SCALL(1, 1, 3);
  SCALL(2, 2, 0); SCALL(2, 2, 1); SCALL(2, 2, 2); SCALL(2, 2, 3);
  asm volatile("s_waitcnt vmcnt(8)" ::: "memory");
  BAR();

  for (int Tb = 0; Tb < 20; Tb += 4) {
    PHASE(0, 3, Tb + 3, 1, 8);
    PHASE(1, 0, Tb + 4, 1, 8);
    PHASE(2, 1, Tb + 5, 1, 8);
    PHASE(3, 2, Tb + 6, 1, 8);
  }
  PHASE(0, 3, 23, 1, 8);
  PHASE(1, 0, 0, 0, 4);
  PHASE(2, 0, 0, 0, 0);
  PHASE(3, 0, 0, 0, -1);

#undef PHASE
#undef SCALL

  float rs[8][4];
#pragma unroll
  for (int m = 0; m < 8; m++)
#pragma unroll
    for (int j = 0; j < 4; j++) rs[m][j] = 0.0f;
  const size_t rowBase = rA0 + (size_t)wr * 128;
  const int colBase = tn * 256 + wc * 64;
#pragma unroll
  for (int mi = 0; mi < 8; mi++) {
    size_t row0 = rowBase + mi * 16 + lq * 4;
#pragma unroll
    for (int nf = 0; nf < 4; nf++) {
      int col = colBase + nf * 16 + lr;
#pragma unroll
      for (int j = 0; j < 4; j++) {
        float e = __expf(acc[mi][nf][j] * scale);
        C[(row0 + j) * 8192 + col] = f2bf(e);
        rs[mi][j] += e;
      }
    }
  }
#pragma unroll
  for (int mi = 0; mi < 8; mi++)
#pragma unroll
    for (int j = 0; j < 4; j++) {
      float r = rs[mi][j];
      r += __shfl_xor(r, 1); r += __shfl_xor(r, 2);
      r += __shfl_xor(r, 4); r += __shfl_xor(r, 8);
      if (lr == 0) atomicAdd(&rowsum[rowBase + mi * 16 + lq * 4 + j], r);
    }
}

// ========== unified fast bt-GEMM: 128x128 tile, BK=32, 4-rot, stage-ahead-3, vmcnt(8) ==========
// The round-12/13-proven schedule (single barrier/phase, counted vmcnt, involution swizzle,
// 64KB LDS -> 2 blocks/CU). 256 thr = 4 waves (2x2 of 64x64). Runtime nk = K/32.
// MODE 0: PV partial — A row stride lda, K-offset z*2048, C = partial bufs, bf16 out
// MODE 2: f32 out + bias[col]
// MODE 3: qkv — tiles tm>=128 (vn rows) write TRANSPOSED into C1 as vnT[col][row-16384]
template <int MODE>
__global__ __launch_bounds__(256, 2) void gemm_fast(
    const u16* __restrict__ A, const u16* __restrict__ B,
    u16* __restrict__ C0, u16* __restrict__ C1,
    int lda, int ldb, int ldc, int nk, int nTn, int cpx,
    const float* __restrict__ bias) {
  __shared__ __align__(16) u16 lds[4 * 8192];  // 64 KB: A bufs 0-3 (32KB) | B bufs 0-3 (32KB)
  const int z = blockIdx.y;
  const int koff = (MODE == 0) ? (z << 11) : 0;
  u16* C = C0;
  if (MODE == 0) C = (z < 2) ? C0 + (size_t)z * 6291456 : C1 + (size_t)(z - 2) * 6291456;
  int orig = blockIdx.x;                       // gridDim.x % 8 == 0
  int wg = (orig & 7) * cpx + (orig >> 3);
  int tm = wg / nTn, tn = wg % nTn;
  const int t = threadIdx.x, l = t & 63, w = t >> 6;
  const int wr = w >> 1, wc = w & 1;           // 2 x 2 wave grid
  const int lr = l & 15, lq = l >> 4;
  const int colb = lq * 16;

  f32x4 acc[4][4];
#pragma unroll
  for (int m = 0; m < 4; m++)
#pragma unroll
    for (int n = 0; n < 4; n++) acc[m][n] = (f32x4){0.f, 0.f, 0.f, 0.f};

  const size_t rA0 = (size_t)tm * 128, rB0 = (size_t)tn * 128;

  // hoisted addressing (idx: 0,1 = A row-halves; 2,3 = B row-halves)
  const char* gsrc[4];
  int ldsoff[4];
#pragma unroll
  for (int idx = 0; idx < 4; idx++) {
    const u16* src = (idx < 2) ? A : B;
    size_t r0 = (idx < 2) ? rA0 : rB0;
    int ld = (idx < 2) ? lda : ldb;
    int p = idx & 1;
    int x = p * 4096 + t * 16;                  // byte offset in 8KB half
    int r = x >> 6;                             // row 0..127
    int cb = (x & 63) ^ (((r >> 1) & 3) << 4);  // pre-swizzled source byte col
    gsrc[idx] = (const char*)(src + (r0 + r) * (size_t)ld + koff) + cb;
    ldsoff[idx] = ((idx < 2) ? 0 : 32768) + p * 4096 + w * 1024;
  }
  int offA[4], offB[4];
#pragma unroll
  for (int mf = 0; mf < 4; mf++) {
    int row = wr * 64 + mf * 16 + lr;
    int x = row * 64 + colb;
    offA[mf] = x ^ (((row >> 1) & 3) << 4);
  }
#pragma unroll
  for (int nf = 0; nf < 4; nf++) {
    int row = wc * 64 + nf * 16 + lr;
    int x = row * 64 + colb;
    offB[nf] = 32768 + (x ^ (((row >> 1) & 3) << 4));
  }

#define GSCALL(BUF, TT, IDX)                                                 \
  gload_lds16(gsrc[IDX] + (size_t)(TT) * 64,                                 \
              (const char*)lds + (BUF) * 8192 + ldsoff[IDX])

  // prologue: stage tiles 0,1,2; wait tile 0 (8 in flight); barrier
  GSCALL(0, 0, 0); GSCALL(0, 0, 1); GSCALL(0, 0, 2); GSCALL(0, 0, 3);
  GSCALL(1, 1, 0); GSCALL(1, 1, 1); GSCALL(1, 1, 2); GSCALL(1, 1, 3);
  GSCALL(2, 2, 0); GSCALL(2, 2, 1); GSCALL(2, 2, 2); GSCALL(2, 2, 3);
  asm volatile("s_waitcnt vmcnt(8)" ::: "memory");
  BAR();

  for (int T = 0; T < nk; T++) {
    const int cur = T & 3;
    bf16x8 aF[4], bF[4];
#pragma unroll
    for (int mf = 0; mf < 4; mf++)
      aF[mf] = *(const bf16x8*)((const char*)lds + cur * 8192 + offA[mf]);
#pragma unroll
    for (int nf = 0; nf < 4; nf++)
      bF[nf] = *(const bf16x8*)((const char*)lds + cur * 8192 + offB[nf]);
    if (T + 3 < nk) {
      const int nb = (T + 3) & 3;
      GSCALL(nb, T + 3, 0); GSCALL(nb, T + 3, 1);
      GSCALL(nb, T + 3, 2); GSCALL(nb, T + 3, 3);
    }
    __builtin_amdgcn_s_setprio(1);
#pragma unroll
    for (int mf = 0; mf < 4; mf++)
#pragma unroll
      for (int nf = 0; nf < 4; nf++)
        acc[mf][nf] = __builtin_amdgcn_mfma_f32_16x16x32_bf16(
            aF[mf], bF[nf], acc[mf][nf], 0, 0, 0);
    __builtin_amdgcn_s_setprio(0);
    if (T < nk - 3)       asm volatile("s_waitcnt vmcnt(8)" ::: "memory");
    else if (T == nk - 3) asm volatile("s_waitcnt vmcnt(4)" ::: "memory");
    else if (T == nk - 2) asm volatile("s_waitcnt vmcnt(0)" ::: "memory");
    BAR();
  }
#undef GSCALL

  // epilogue (C/D layout col=lane&15, row=(lane>>4)*4+j)
#pragma unroll
  for (int mf = 0; mf < 4; mf++) {
    int row = tm * 128 + wr * 64 + mf * 16 + lq * 4;
#pragma unroll
    for (int nf = 0; nf < 4; nf++) {
      int col = tn * 128 + wc * 64 + nf * 16 + lr;
      if (MODE == 2) {
#pragma unroll
        for (int j = 0; j < 4; j++)
          ((float*)C0)[(size_t)(row + j) * ldc + col] = acc[mf][nf][j] + bias[col];
      } else if (MODE == 3 && tm >= 128) {
        ushort4 o;
        o.x = f2bf(acc[mf][nf][0]); o.y = f2bf(acc[mf][nf][1]);
        o.z = f2bf(acc[mf][nf][2]); o.w = f2bf(acc[mf][nf][3]);
        *(ushort4*)(C1 + (size_t)col * 8192 + (row - 16384)) = o;
      } else {
#pragma unroll
        for (int j = 0; j < 4; j++)
          C[(size_t)(row + j) * ldc + col] = f2bf(acc[mf][nf][j]);
      }
    }
  }
}

// ---------------- host ----------------
extern "C" void kernel_launch(void* const* d_in, const int* in_sizes, int n_in,
                              void* d_out, int out_size, void* d_ws, size_t ws_size,
                              hipStream_t stream) {
  const float* q  = (const float*)d_in[0];
  const float* k  = (const float*)d_in[1];
  const float* v  = (const float*)d_in[2];
  const float* lw = (const float*)d_in[3];
  const float* lb = (const float*)d_in[4];
  const float* Wq = (const float*)d_in[5];
  const float* Wp = (const float*)d_in[6];
  const float* bp = (const float*)d_in[7];

  char* ws = (char*)d_ws;
  size_t off = 0;
  auto alloc = [&](size_t b) { size_t o = off; off += (b + 255) & ~(size_t)255; return o; };
  size_t o_ln = alloc((size_t)24576 * 768 * 2);  // LN(q,k,v) bf16; later: rowsum | p0 | p1
  size_t o_pj = alloc((size_t)24576 * 768 * 2);  // qn,kn bf16 | vnT (written by qkv MODE 3)
  size_t o_wq = alloc((size_t)768 * 768 * 2);
  size_t o_wp = alloc((size_t)768 * 768 * 2);
  u16* lnbuf = (u16*)(ws + o_ln);
  u16* pj    = (u16*)(ws + o_pj);
  u16* wqb   = (u16*)(ws + o_wq);
  u16* wpb   = (u16*)(ws + o_wp);
  const size_t NS = (size_t)8192 * 768;
  float* rowsum = (float*)lnbuf;           // lnbuf dead after qkv reads it
  u16* p0 = lnbuf + NS;
  u16* p1 = lnbuf + 2 * NS;
  u16* vnT = pj + 2 * NS;                  // vn slot holds TRANSPOSED vn (qkv MODE 3)
  u16* p2 = (u16*)d_out;                   // partials 2,3 in d_out (overwritten by proj)
  u16* p3 = p2 + NS;
  size_t fixedEnd = off;
  u16* Sbuf = (u16*)(ws + fixedEnd);       // P' = exp(S*scale) bf16, 8192x8192

  const float scale = 0.03608439182435161f;  // 1/sqrt(768)

  ln_cast_kernel<<<dim3(24576), dim3(256), 0, stream>>>(q, k, v, lw, lb, lnbuf);
  cast2_f32_bf16<<<dim3(1152), dim3(256), 0, stream>>>(Wq, Wp, wqb, wpb);

  // qn/kn -> pj rows [0,16384); vn -> TRANSPOSED into vnT (MODE 3). nk=24, nTn=6, cpx=144
  gemm_fast<3><<<dim3(1152), dim3(256), 0, stream>>>(lnbuf, wqb, pj, vnT,
      768, 768, 768, 24, 6, 144, (const float*)nullptr);

  zero_f32<<<dim3(32), dim3(256), 0, stream>>>(rowsum, 8192);

  // P' = exp(qn @ kn^T * scale), rowsum via atomics
  qk_exp_256<<<dim3(1024), dim3(512), 0, stream>>>(pj, pj + NS, Sbuf, rowsum, scale);

  // attn partials = P' @ vn, 4-way split-K. nk=64, nTn=6, cpx=48
  gemm_fast<0><<<dim3(384, 4), dim3(256), 0, stream>>>(Sbuf, vnT, p0, p2,
      8192, 8192, 768, 64, 6, 48, (const float*)nullptr);

  // attn_out = (p0+p1+p2+p3) / rowsum
  reduce4_scale<<<dim3(3072), dim3(256), 0, stream>>>(p0, p1, p2, p3, rowsum, p0, (int)(NS / 8));

  // out = attn_out @ W_proj^T + b_proj. nk=24, nTn=6, cpx=48
  gemm_fast<2><<<dim3(384), dim3(256), 0, stream>>>(p0, wpb, (u16*)d_out, (u16*)nullptr,
      768, 768, 768, 24, 6, 48, bp);
}